// Round 2
// baseline (191.407 us; speedup 1.0000x reference)
//
#include <hip/hip_runtime.h>

// LinearAttention: B=2, L=2048, D=1024, H=16, d=64.
// cvt_all ; QKV GEMM (R7: quad-buffered counted-vmcnt) ; kv_local ; kv_prefix ;
// attn_chunk ; out GEMM.
// R6 post-mortem: tile-granular dbuf forced vmcnt(0) drains at every K-tile
// boundary (= m218's "8ph with drain0" null, ~650 TF). R7: 4 buffers of BK=32,
// 3-tiles-deep prefetch, publish waits are s_waitcnt vmcnt(8) (tiles i+2,i+3
// stay in flight) -- never 0 in the main loop. LDS is fragment-blocked so the
// global_load_lds lane order IS the ds_read order: conflict-free, no swizzle.

#define DEV __device__ __forceinline__

typedef __attribute__((ext_vector_type(8))) short bf16x8;
typedef __attribute__((ext_vector_type(4))) float f32x4;

DEV ushort f2bf(float f) {
  union { float f; unsigned u; } v; v.f = f;
  unsigned r = v.u + 0x7fffu + ((v.u >> 16) & 1u);
  return (ushort)(r >> 16);
}
DEV float bf2f(unsigned b) {
  union { unsigned u; float f; } v; v.u = (b & 0xffffu) << 16;
  return v.f;
}
DEV void glds16(const ushort* g, ushort* l) {
  __builtin_amdgcn_global_load_lds(
      (const __attribute__((address_space(1))) unsigned int*)g,
      (__attribute__((address_space(3))) unsigned int*)l, 16, 0, 0);
}

__global__ __launch_bounds__(256) void cvt_all(const float* __restrict__ x,
                                               const float* __restrict__ Ww,
                                               const float* __restrict__ Ow,
                                               ushort* __restrict__ xb,
                                               ushort* __restrict__ wqkvb,
                                               ushort* __restrict__ outwb) {
  int i = blockIdx.x * 256 + threadIdx.x;
  const float* src; ushort* dst; int off;
  if (i < 1048576)      { src = x;  dst = xb;    off = i; }
  else if (i < 1835008) { src = Ww; dst = wqkvb; off = i - 1048576; }
  else                  { src = Ow; dst = outwb; off = i - 1835008; }
  float4 v = ((const float4*)src)[off];
  ushort4 o;
  o.x = f2bf(v.x); o.y = f2bf(v.y); o.z = f2bf(v.z); o.w = f2bf(v.w);
  ((ushort4*)dst)[off] = o;
}

// ---------------------------------------------------------------------------
// Quad-buffered 256x256 GEMM: C = A[M,K]*Bw[N,K]^T + bias.
// 512 threads = 8 waves (2M x 4N), per-wave output 128x64 (8x4 fragments).
// BK=32, 4 LDS buffers (128 KiB total), prefetch depth 3 tiles.
// Per tile i: [stage A of tile i+3] reads(B0-3,A0-3) BAR MFMA16 BAR
//             [stage B of tile i+3] reads(A4-7)      BAR MFMA16
//             publish: vmcnt(8) [i<NT-3] / vmcnt(4) [i==NT-3] / vmcnt(0) BAR.
// vmcnt(8) = tiles i+2,i+3 (4 glds/thread each) remain in flight; in-order
// counter release guarantees tile i+1 is resident. Requires NT >= 4.
// LDS fragment-blocked layout: frag f (16 rows x 32 cols) occupies 1 KiB at
// f*512 ushorts, element (row=f*16+l16, k=quad*8+j) at quad*128+l16*8+j.
// global_load_lds writes base+lane*16B with lane=(quad,l16) -> staging source
// row = (call*8+wid)*16+l16, col = quad*8: layout identity, reads contiguous
// 1 KiB per fragment per wave => bank-conflict-free without swizzle.
// ---------------------------------------------------------------------------
template <bool OUT_BF16, bool KSCALE>
__global__ __launch_bounds__(512, 2) void gemm_bt8(const ushort* __restrict__ A,
                                                   const ushort* __restrict__ Bw,
                                                   const float* __restrict__ bias,
                                                   void* __restrict__ Cout,
                                                   int M, int N, int K) {
  __shared__ __align__(16) ushort As[4][8192];
  __shared__ __align__(16) ushort Bs[4][8192];
  const int t = threadIdx.x;
  const int lane = t & 63, wid = t >> 6;
  const int quad = lane >> 4, l16 = lane & 15;
  const int wm2 = wid >> 2, wn4 = wid & 3;

  // T1: bijective XCD swizzle (gridDim.x % 8 == 0).
  const int nwg = gridDim.x;
  const int bid = blockIdx.x;
  const int wg = (bid & 7) * (nwg >> 3) + (bid >> 3);
  const int nbx = N >> 8;
  const int bx = wg % nbx, by = wg / nbx;
  const int bm = by << 8, bn = bx << 8;

  // Staging source: thread (wid,quad,l16), call c covers frag f = c*8+wid.
  const ushort* agA = A + (size_t)(bm + wid * 16 + l16) * K + quad * 8;
  const ushort* bgB = Bw + (size_t)(bn + wid * 16 + l16) * K + quad * 8;
  const size_t cskip = (size_t)128 * K;  // 8 frags * 16 rows per call

  const int NT = K >> 5;  // K-tiles of 32 (assumed >= 4)

  f32x4 acc[8][4];
  const f32x4 z = {0.f, 0.f, 0.f, 0.f};
#pragma unroll
  for (int i = 0; i < 8; ++i)
#pragma unroll
    for (int j = 0; j < 4; ++j) acc[i][j] = z;

  const int rdA = (wm2 * 8) * 512 + quad * 128 + l16 * 8;  // + mi*512
  const int rdB = (wn4 * 4) * 512 + quad * 128 + l16 * 8;  // + nj*512
  const int wdst = wid * 512;                              // + call*4096

#define SG_A(bufi, kt, c) \
  glds16(agA + (size_t)(c) * cskip + ((kt) << 5), &As[bufi][(c)*4096 + wdst])
#define SG_B(bufi, kt, c) \
  glds16(bgB + (size_t)(c) * cskip + ((kt) << 5), &Bs[bufi][(c)*4096 + wdst])
#define RD_A(bufi, mi) (*(const bf16x8*)&As[bufi][rdA + (mi)*512])
#define RD_B(bufi, nj) (*(const bf16x8*)&Bs[bufi][rdB + (nj)*512])

  // Prologue: tiles 0,1,2 -> bufs 0,1,2; wait tile 0 (tiles 1,2 in flight).
  SG_A(0, 0, 0); SG_A(0, 0, 1); SG_B(0, 0, 0); SG_B(0, 0, 1);
  SG_A(1, 1, 0); SG_A(1, 1, 1); SG_B(1, 1, 0); SG_B(1, 1, 1);
  SG_A(2, 2, 0); SG_A(2, 2, 1); SG_B(2, 2, 0); SG_B(2, 2, 1);
  asm volatile("s_waitcnt vmcnt(8)" ::: "memory");
  __builtin_amdgcn_s_barrier();

  for (int i = 0; i < NT; ++i) {
    const int rb = i & 3;
    const int sb = (i + 3) & 3;
    const bool doSt = (i + 3) < NT;

    // phase 1: stage A of tile i+3; read all B frags + A frags 0-3.
    if (doSt) { SG_A(sb, i + 3, 0); SG_A(sb, i + 3, 1); }
    bf16x8 b0 = RD_B(rb, 0), b1 = RD_B(rb, 1), b2 = RD_B(rb, 2), b3 = RD_B(rb, 3);
    bf16x8 a0 = RD_A(rb, 0), a1 = RD_A(rb, 1), a2 = RD_A(rb, 2), a3 = RD_A(rb, 3);
    __builtin_amdgcn_s_barrier();
    __builtin_amdgcn_s_setprio(1);
    acc[0][0] = __builtin_amdgcn_mfma_f32_16x16x32_bf16(a0, b0, acc[0][0], 0, 0, 0);
    acc[0][1] = __builtin_amdgcn_mfma_f32_16x16x32_bf16(a0, b1, acc[0][1], 0, 0, 0);
    acc[0][2] = __builtin_amdgcn_mfma_f32_16x16x32_bf16(a0, b2, acc[0][2], 0, 0, 0);
    acc[0][3] = __builtin_amdgcn_mfma_f32_16x16x32_bf16(a0, b3, acc[0][3], 0, 0, 0);
    acc[1][0] = __builtin_amdgcn_mfma_f32_16x16x32_bf16(a1, b0, acc[1][0], 0, 0, 0);
    acc[1][1] = __builtin_amdgcn_mfma_f32_16x16x32_bf16(a1, b1, acc[1][1], 0, 0, 0);
    acc[1][2] = __builtin_amdgcn_mfma_f32_16x16x32_bf16(a1, b2, acc[1][2], 0, 0, 0);
    acc[1][3] = __builtin_amdgcn_mfma_f32_16x16x32_bf16(a1, b3, acc[1][3], 0, 0, 0);
    acc[2][0] = __builtin_amdgcn_mfma_f32_16x16x32_bf16(a2, b0, acc[2][0], 0, 0, 0);
    acc[2][1] = __builtin_amdgcn_mfma_f32_16x16x32_bf16(a2, b1, acc[2][1], 0, 0, 0);
    acc[2][2] = __builtin_amdgcn_mfma_f32_16x16x32_bf16(a2, b2, acc[2][2], 0, 0, 0);
    acc[2][3] = __builtin_amdgcn_mfma_f32_16x16x32_bf16(a2, b3, acc[2][3], 0, 0, 0);
    acc[3][0] = __builtin_amdgcn_mfma_f32_16x16x32_bf16(a3, b0, acc[3][0], 0, 0, 0);
    acc[3][1] = __builtin_amdgcn_mfma_f32_16x16x32_bf16(a3, b1, acc[3][1], 0, 0, 0);
    acc[3][2] = __builtin_amdgcn_mfma_f32_16x16x32_bf16(a3, b2, acc[3][2], 0, 0, 0);
    acc[3][3] = __builtin_amdgcn_mfma_f32_16x16x32_bf16(a3, b3, acc[3][3], 0, 0, 0);
    __builtin_amdgcn_s_setprio(0);
    __builtin_amdgcn_s_barrier();

    // phase 2: stage B of tile i+3; read A frags 4-7.
    if (doSt) { SG_B(sb, i + 3, 0); SG_B(sb, i + 3, 1); }
    a0 = RD_A(rb, 4); a1 = RD_A(rb, 5); a2 = RD_A(rb, 6); a3 = RD_A(rb, 7);
    __builtin_amdgcn_s_barrier();
    __builtin_amdgcn_s_setprio(1);
    acc[4][0] = __builtin_amdgcn_mfma_f32_16x16x32_bf16(a0, b0, acc[4][0], 0, 0, 0);
    acc[4][1] = __builtin_amdgcn_mfma_f32_16x16x32_bf16(a0, b1, acc[4][1], 0, 0, 0);
    acc[4][2] = __builtin_amdgcn_mfma_f32_16x16x32_bf16(a0, b2, acc[4][2], 0, 0, 0);
    acc[4][3] = __builtin_amdgcn_mfma_f32_16x16x32_bf16(a0, b3, acc[4][3], 0, 0, 0);
    acc[5][0] = __builtin_amdgcn_mfma_f32_16x16x32_bf16(a1, b0, acc[5][0], 0, 0, 0);
    acc[5][1] = __builtin_amdgcn_mfma_f32_16x16x32_bf16(a1, b1, acc[5][1], 0, 0, 0);
    acc[5][2] = __builtin_amdgcn_mfma_f32_16x16x32_bf16(a1, b2, acc[5][2], 0, 0, 0);
    acc[5][3] = __builtin_amdgcn_mfma_f32_16x16x32_bf16(a1, b3, acc[5][3], 0, 0, 0);
    acc[6][0] = __builtin_amdgcn_mfma_f32_16x16x32_bf16(a2, b0, acc[6][0], 0, 0, 0);
    acc[6][1] = __builtin_amdgcn_mfma_f32_16x16x32_bf16(a2, b1, acc[6][1], 0, 0, 0);
    acc[6][2] = __builtin_amdgcn_mfma_f32_16x16x32_bf16(a2, b2, acc[6][2], 0, 0, 0);
    acc[6][3] = __builtin_amdgcn_mfma_f32_16x16x32_bf16(a2, b3, acc[6][3], 0, 0, 0);
    acc[7][0] = __builtin_amdgcn_mfma_f32_16x16x32_bf16(a3, b0, acc[7][0], 0, 0, 0);
    acc[7][1] = __builtin_amdgcn_mfma_f32_16x16x32_bf16(a3, b1, acc[7][1], 0, 0, 0);
    acc[7][2] = __builtin_amdgcn_mfma_f32_16x16x32_bf16(a3, b2, acc[7][2], 0, 0, 0);
    acc[7][3] = __builtin_amdgcn_mfma_f32_16x16x32_bf16(a3, b3, acc[7][3], 0, 0, 0);
    __builtin_amdgcn_s_setprio(0);

    // publish tile i+1 (counted: tiles i+2,i+3 stay in flight).
    if (i < NT - 1) {
      if (i < NT - 3)       asm volatile("s_waitcnt vmcnt(8)" ::: "memory");
      else if (i == NT - 3) asm volatile("s_waitcnt vmcnt(4)" ::: "memory");
      else                  asm volatile("s_waitcnt vmcnt(0)" ::: "memory");
      __builtin_amdgcn_s_barrier();
    }
  }

#undef SG_A
#undef SG_B
#undef RD_A
#undef RD_B

#pragma unroll
  for (int mi = 0; mi < 8; ++mi)
#pragma unroll
    for (int nj = 0; nj < 4; ++nj) {
      const int col = bn + wn4 * 64 + nj * 16 + l16;
      const float bv = bias[col];
      float sc = 1.f;
      if (KSCALE) sc = ((col >> 10) == 1) ? 0.125f : 1.f;
#pragma unroll
      for (int r = 0; r < 4; ++r) {
        const int row = bm + wm2 * 128 + mi * 16 + quad * 4 + r;
        const float v = (acc[mi][nj][r] + bv) * sc;
        if (OUT_BF16)
          ((ushort*)Cout)[(size_t)row * N + col] = f2bf(v);
        else
          ((float*)Cout)[(size_t)row * N + col] = v;
      }
    }
}

// Out projection: BM=64, BN=128, BK=32 -> 512 blocks (2/CU), identity staging.
__global__ __launch_bounds__(256) void gemm_out64(const ushort* __restrict__ A,
                                                  const ushort* __restrict__ Bw,
                                                  const float* __restrict__ bias,
                                                  float* __restrict__ C,
                                                  int M, int N, int K) {
  __shared__ ushort As[64 * 32];
  __shared__ ushort Bs[128 * 32];
  const int t = threadIdx.x;
  const int wid = t >> 6, lane = t & 63;
  const int quad = lane >> 4, l16 = lane & 15;
  const int bm = blockIdx.y * 64, bn = blockIdx.x * 128;
  const int wn = wid * 32;

  f32x4 acc[4][2];
  const f32x4 z = {0.f, 0.f, 0.f, 0.f};
#pragma unroll
  for (int i = 0; i < 4; ++i) { acc[i][0] = z; acc[i][1] = z; }

  const ushort* ag = A + (size_t)(bm + (t >> 2)) * K + ((t & 3) * 8);
  const ushort* bg = Bw + (size_t)(bn + (t >> 2)) * K + ((t & 3) * 8);
  ushort* asl = As + wid * 512;
  ushort* bsl = Bs + wid * 512;
  const size_t rowskip = (size_t)64 * K;

  for (int k0 = 0; k0 < K; k0 += 32) {
    glds16(ag + k0, asl);
    glds16(bg + k0, bsl);
    glds16(bg + k0 + rowskip, bsl + 2048);
    __syncthreads();
    bf16x8 af[4], bf[2];
#pragma unroll
    for (int i = 0; i < 4; ++i)
      af[i] = *(const bf16x8*)(As + (i * 16 + l16) * 32 + quad * 8);
#pragma unroll
    for (int j = 0; j < 2; ++j)
      bf[j] = *(const bf16x8*)(Bs + (wn + j * 16 + l16) * 32 + quad * 8);
#pragma unroll
    for (int i = 0; i < 4; ++i)
#pragma unroll
      for (int j = 0; j < 2; ++j)
        acc[i][j] = __builtin_amdgcn_mfma_f32_16x16x32_bf16(af[i], bf[j], acc[i][j], 0, 0, 0);
    __syncthreads();
  }

#pragma unroll
  for (int i = 0; i < 4; ++i)
#pragma unroll
    for (int j = 0; j < 2; ++j) {
      const int col = bn + wn + j * 16 + l16;
      const float bv = bias[col];
#pragma unroll
      for (int r = 0; r < 4; ++r) {
        const int row = bm + i * 16 + quad * 4 + r;
        C[(size_t)row * N + col] = acc[i][j][r] + bv;
      }
    }
}

// Per-(bh,chunk) KV sums via MFMA: mlocT[bh][c][e][f] = sum_s v[s][e]*k[s][f].
__global__ __launch_bounds__(256) void kv_local(const ushort* __restrict__ qkv,
                                                float* __restrict__ mlocT) {
  const int c = blockIdx.x, bh = blockIdx.y;
  const int b = bh >> 4, hd = bh & 15;
  const int t = threadIdx.x;
  const int wid = t >> 6, lane = t & 63;
  const int quad = lane >> 4, l16 = lane & 15;
  __shared__ ushort kT[64 * 136];  // [f:64][s:128] pad 8
  __shared__ ushort vT[64 * 136];  // [e:64][s:128] pad 8

  {
    const int row = t & 127;
    const int isv = t >> 7;
    const ushort* g = qkv + (size_t)(b * 2048 + c * 128 + row) * 3072 +
                      1024 + isv * 1024 + hd * 64;
    ushort tmp[64];
#pragma unroll
    for (int q = 0; q < 8; ++q) *(uint4*)(tmp + q * 8) = *(const uint4*)(g + q * 8);
    ushort* dst = isv ? vT : kT;
#pragma unroll
    for (int j = 0; j < 64; ++j) dst[j * 136 + row] = tmp[j];
  }
  __syncthreads();

  const f32x4 z = {0.f, 0.f, 0.f, 0.f};
  f32x4 acc[4];
#pragma unroll
  for (int ct = 0; ct < 4; ++ct) acc[ct] = z;
#pragma unroll
  for (int kc = 0; kc < 4; ++kc) {
    bf16x8 afr = *(const bf16x8*)(vT + (wid * 16 + l16) * 136 + kc * 32 + quad * 8);
#pragma unroll
    for (int ct = 0; ct < 4; ++ct) {
      bf16x8 bfr = *(const bf16x8*)(kT + (ct * 16 + l16) * 136 + kc * 32 + quad * 8);
      acc[ct] = __builtin_amdgcn_mfma_f32_16x16x32_bf16(afr, bfr, acc[ct], 0, 0, 0);
    }
  }

  float* outp = mlocT + ((size_t)bh * 16 + c) * 4096;
#pragma unroll
  for (int ct = 0; ct < 4; ++ct)
#pragma unroll
    for (int r = 0; r < 4; ++r)
      outp[(wid * 16 + quad * 4 + r) * 64 + ct * 16 + l16] = acc[ct][r];
}

// Exclusive prefix over chunks, parallel over 4096 (e,f) entries per bh.
__global__ __launch_bounds__(256) void kv_prefix(const float* __restrict__ mlocT,
                                                 ushort* __restrict__ statesT) {
  const int slice = blockIdx.x, bh = blockIdx.y;
  const int eidx = slice * 256 + threadIdx.x;
  float run = 0.f;
  for (int c = 0; c < 16; ++c) {
    const size_t idx = ((size_t)bh * 16 + c) * 4096 + eidx;
    statesT[idx] = f2bf(run);
    run += mlocT[idx];
  }
}

// Per-(bh,chunk): P = tril(Q K^T) ; Y = P V + Q S_prefix (state from statesT).
__global__ __launch_bounds__(256) void attn_chunk(const ushort* __restrict__ qkv,
                                                  const ushort* __restrict__ statesT,
                                                  ushort* __restrict__ yb) {
  const int c = blockIdx.x, bh = blockIdx.y;
  const int b = bh >> 4, hd = bh & 15;
  const int l0 = c * 128;
  const int t = threadIdx.x;
  const int wid = t >> 6, lane = t & 63;
  const int quad = lane >> 4, l16 = lane & 15;

  __shared__ ushort P[16384];  // [row][16B chunks] XOR-swizzled by row&7
  __shared__ ushort U[16384];
  ushort* Qs = U;              // [row:128][64] chunk^(row&7)
  ushort* Ks = U + 8192;
  ushort* vT = U;              // phase2: [e:64][s:128] stride 136
  ushort* sT = U + 8704;       // phase2: [e:64][f:64]  stride 72

  {  // zero P
    uint4 zz; zz.x = zz.y = zz.z = zz.w = 0u;
    uint4* p4 = (uint4*)P;
#pragma unroll
    for (int i = 0; i < 8; ++i) p4[i * 256 + t] = zz;
  }
  {  // stage Q,K swizzled
    const int kcs = ((lane & 7) ^ (lane >> 3)) * 8;
    const ushort* qg = qkv + (size_t)(b * 2048 + l0 + (t >> 3)) * 3072 + hd * 64 + kcs;
    ushort* ql = Qs + wid * 512;
    ushort* kl = Ks + wid * 512;
#pragma unroll
    for (int h2 = 0; h2 < 4; ++h2) {
      glds16(qg + (size_t)h2 * 32 * 3072, ql + h2 * 2048);
      glds16(qg + (size_t)h2 * 32 * 3072 + 1024, kl + h2 * 2048);
    }
  }
  __syncthreads();

  bf16x8 qf[2][2];
#pragma unroll
  for (int i = 0; i < 2; ++i)
#pragma unroll
    for (int kc = 0; kc < 2; ++kc)
      qf[i][kc] = *(const bf16x8*)(Qs + ((wid * 2 + i) * 16 + l16) * 64 +
                                   (((kc * 4 + quad) ^ (l16 & 7)) * 8));

  const f32x4 z4 = {0.f, 0.f, 0.f, 0.f};
  f32x4 pacc[2][8];
#pragma unroll
  for (int i = 0; i < 2; ++i)
#pragma unroll
    for (int j = 0; j < 8; ++j) pacc[i][j] = z4;

#pragma unroll
  for (int i = 0; i < 2; ++i) {
    const int rt = wid * 2 + i;
#pragma unroll
    for (int tj = 0; tj < 8; ++tj) {
      if (tj <= rt) {
#pragma unroll
        for (int kc = 0; kc < 2; ++kc) {
          bf16x8 kfr = *(const bf16x8*)(Ks + (tj * 16 + l16) * 64 +
                                        (((kc * 4 + quad) ^ (l16 & 7)) * 8));
          pacc[i][tj] = __builtin_amdgcn_mfma_f32_16x16x32_bf16(qf[i][kc], kfr, pacc[i][tj], 0, 0, 0);
        }
      }
    }
  }
  __syncthreads();

#pragma unroll
  for (int i = 0; i < 2; ++i) {
    const int rt = wid * 2 + i;
#pragma unroll
    for (int tj = 0; tj < 8; ++tj) {
      if (tj <= rt) {
#pragma unroll
        for (int r = 0; r < 4; ++r) {
          const int row = rt * 16 + quad * 4 + r;
          const int scol = tj * 16 + l16;
          const float v = (scol <= row) ? pacc[i][tj][r] : 0.f;
          P[row * 128 + (((scol >> 3) ^ (row & 7)) * 8) + (scol & 7)] = f2bf(v);
        }
      }
    }
  }
  {  // stage V transposed: vT[e][s], stride 136
    const int sstep = t >> 1, eb = (t & 1) * 32;
    const ushort* vg = qkv + (size_t)(b * 2048 + l0 + sstep) * 3072 + 2048 + hd * 64 + eb;
    ushort tmp[32];
    *(uint4*)(tmp + 0)  = *(const uint4*)(vg + 0);
    *(uint4*)(tmp + 8)  = *(const uint4*)(vg + 8);
    *(uint4*)(tmp + 16) = *(const uint4*)(vg + 16);
    *(uint4*)(tmp + 24) = *(const uint4*)(vg + 24);
#pragma unroll
    for (int j = 0; j < 32; ++j) vT[(eb + j) * 136 + sstep] = tmp[j];
  }
  {  // stage state: 2 coalesced uint4 per thread -> sT stride 72
    const ushort* sg = statesT + ((size_t)bh * 16 + c) * 4096;
#pragma unroll
    for (int h = 0; h < 2; ++h) {
      const int cc = h * 256 + t;
      uint4 d = *(const uint4*)(sg + cc * 8);
      *(uint4*)(sT + (cc >> 3) * 72 + (cc & 7) * 8) = d;
    }
  }
  __syncthreads();

  f32x4 yacc[2][4];
#pragma unroll
  for (int i = 0; i < 2; ++i)
#pragma unroll
    for (int j = 0; j < 4; ++j) yacc[i][j] = z4;

#pragma unroll
  for (int i = 0; i < 2; ++i) {
    const int rt = wid * 2 + i;
    const int kcmax = rt >> 1;
#pragma unroll
    for (int kc = 0; kc < 4; ++kc) {
      if (kc <= kcmax) {
        const int prow = rt * 16 + l16;
        bf16x8 pf;
        *(uint4*)&pf = *(const uint4*)(P + prow * 128 + (((kc * 4 + quad) ^ (prow & 7)) * 8));
#pragma unroll
        for (int ct = 0; ct < 4; ++ct) {
          bf16x8 vf = *(const bf16x8*)(vT + (ct * 16 + l16) * 136 + kc * 32 + quad * 8);
          yacc[i][ct] = __builtin_amdgcn_mfma_f32_16x16x32_bf16(pf, vf, yacc[i][ct], 0, 0, 0);
        }
      }
    }
#pragma unroll
    for (int kc = 0; kc < 2; ++kc) {
#pragma unroll
      for (int ct = 0; ct < 4; ++ct) {
        bf16x8 sf = *(const bf16x8*)(sT + (ct * 16 + l16) * 72 + kc * 32 + quad * 8);
        yacc[i][ct] = __builtin_amdgcn_mfma_f32_16x16x32_bf16(qf[i][kc], sf, yacc[i][ct], 0, 0, 0);
      }
    }
  }

#pragma unroll
  for (int i = 0; i < 2; ++i) {
    const int rt = wid * 2 + i;
#pragma unroll
    for (int ct = 0; ct < 4; ++ct) {
#pragma unroll
      for (int r = 0; r < 4; ++r) {
        const int row = rt * 16 + quad * 4 + r;
        const int e = ct * 16 + l16;
        yb[(size_t)(b * 2048 + l0 + row) * 1024 + hd * 64 + e] = f2bf(yacc[i][ct][r]);
      }
    }
  }
}

extern "C" void kernel_launch(void* const* d_in, const int* in_sizes, int n_in,
                              void* d_out, int out_size, void* d_ws, size_t ws_size,
                              hipStream_t stream) {
  const float* x  = (const float*)d_in[0];
  const float* Ww = (const float*)d_in[1];
  const float* Wb = (const float*)d_in[2];
  const float* Ow = (const float*)d_in[3];
  const float* Ob = (const float*)d_in[4];
  float* out = (float*)d_out;

  char* ws = (char*)d_ws;
  ushort* xb      = (ushort*)(ws);
  ushort* wqkvb   = (ushort*)(ws + (size_t)8  * 1024 * 1024);
  ushort* outwb   = (ushort*)(ws + (size_t)14 * 1024 * 1024);
  ushort* qkvb    = (ushort*)(ws + (size_t)16 * 1024 * 1024);
  float*  mlocT   = (float*) (ws + (size_t)40 * 1024 * 1024);
  ushort* statesT = (ushort*)(ws + (size_t)48 * 1024 * 1024);
  ushort* yb      = (ushort*)(ws + (size_t)52 * 1024 * 1024);

  cvt_all<<<8192, 256, 0, stream>>>(x, Ww, Ow, xb, wqkvb, outwb);
  // 256^2 tiles: grid = (3072/256)*(4096/256) = 192 blocks (1D, XCD-swizzled).
  gemm_bt8<true, true><<<dim3(192), 512, 0, stream>>>(xb, wqkvb, Wb, (void*)qkvb, 4096, 3072, 1024);
  kv_local<<<dim3(16, 32), 256, 0, stream>>>(qkvb, mlocT);
  kv_prefix<<<dim3(16, 32), 256, 0, stream>>>(mlocT, statesT);
  attn_chunk<<<dim3(16, 32), 256, 0, stream>>>(qkvb, statesT, yb);
  gemm_out64<<<dim3(8, 64), 256, 0, stream>>>(yb, outwb, Ob, out, 4096, 1024, 1024);
}

// Round 3
// 163.784 us; speedup vs baseline: 1.1687x; 1.1687x over previous
//
#include <hip/hip_runtime.h>

// LinearAttention: B=2, L=2048, D=1024, H=16, d=64.
// cvt_all ; QKV GEMM (R8: gemm_loose 256x192, 1 barrier/K-tile) ; kv_local ;
// kv_prefix ; attn_chunk ; out GEMM (R0-proven 128^2 gemm_bt).
// R7 post-mortem: lockstep counted-vmcnt quad-buffer was 72us -- schedule
// overhead at 1 block/CU dwarfed the 320cy/SIMD of MFMA per tile. R8 bets on
// the opposite (m97 mechanism): 256x192 tiles fill all 256 CUs (16x16 grid),
// BK=64 dbuf with ONE vmcnt(0)+barrier per K-tile, everything else left to
// the compiler + wave slip. R6 swizzle kept (pre-swizzled glds source + XOR
// ds_read: 2-way conflicts = free).

#define DEV __device__ __forceinline__

typedef __attribute__((ext_vector_type(8))) short bf16x8;
typedef __attribute__((ext_vector_type(4))) float f32x4;

DEV ushort f2bf(float f) {
  union { float f; unsigned u; } v; v.f = f;
  unsigned r = v.u + 0x7fffu + ((v.u >> 16) & 1u);
  return (ushort)(r >> 16);
}
DEV float bf2f(unsigned b) {
  union { unsigned u; float f; } v; v.u = (b & 0xffffu) << 16;
  return v.f;
}
DEV void glds16(const ushort* g, ushort* l) {
  __builtin_amdgcn_global_load_lds(
      (const __attribute__((address_space(1))) unsigned int*)g,
      (__attribute__((address_space(3))) unsigned int*)l, 16, 0, 0);
}

__global__ __launch_bounds__(256) void cvt_all(const float* __restrict__ x,
                                               const float* __restrict__ Ww,
                                               const float* __restrict__ Ow,
                                               ushort* __restrict__ xb,
                                               ushort* __restrict__ wqkvb,
                                               ushort* __restrict__ outwb) {
  int i = blockIdx.x * 256 + threadIdx.x;
  const float* src; ushort* dst; int off;
  if (i < 1048576)      { src = x;  dst = xb;    off = i; }
  else if (i < 1835008) { src = Ww; dst = wqkvb; off = i - 1048576; }
  else                  { src = Ow; dst = outwb; off = i - 1835008; }
  float4 v = ((const float4*)src)[off];
  ushort4 o;
  o.x = f2bf(v.x); o.y = f2bf(v.y); o.z = f2bf(v.z); o.w = f2bf(v.w);
  ((ushort4*)dst)[off] = o;
}

// ---------------------------------------------------------------------------
// QKV GEMM, hardcoded M=4096 N=3072 K=1024: qkv = xb * Wqkv^T + b, bf16 out,
// K-block (cols 1024..2047) scaled by 0.125.
// BM=256, BN=192, BK=64 -> grid 16x16 = 256 blocks (full chip, 1/CU).
// 512 thr = 8 waves (2M x 4N); per-wave 128x48 output = 8x3 fragments.
// LDS: A 2x32KB + B 2x24KB = 112 KB double-buffer.
// Schedule per K-tile (LOOSE -- one sync point only):
//   [7 glds stage tile i+1] [22 ds_read + 48 MFMA, compiler-scheduled]
//   [vmcnt(0) ; s_barrier]
// Correctness: buffer sb was last read in region i-1 (before that region's
// barrier); glds to sb issued in region i (after it). Drain-before-swap means
// no counted-wait hazard exists anywhere.
// Swizzle (rule #21 both-sides): LDS[row][pc] holds logical chunk pc^(row&7);
// staged via pre-swizzled GLOBAL column ((t&7)^(row&7))*8 with linear LDS
// dest; read at phys chunk (kc*4+quad)^(l16&7). 2-way bank alias only (free).
// ---------------------------------------------------------------------------
__global__ __launch_bounds__(512, 2) void gemm_loose(const ushort* __restrict__ A,
                                                     const ushort* __restrict__ Bw,
                                                     const float* __restrict__ bias,
                                                     ushort* __restrict__ Cout) {
  __shared__ __align__(16) ushort As[2][16384];  // 256 x 64
  __shared__ __align__(16) ushort Bs[2][12288];  // 192 x 64
  const int t = threadIdx.x;
  const int lane = t & 63, wid = t >> 6;
  const int quad = lane >> 4, l16 = lane & 15;
  const int wm2 = wid >> 2, wn4 = wid & 3;
  const int K = 1024, N = 3072;

  // T1: bijective XCD swizzle (256 blocks, 256 % 8 == 0).
  const int bid = blockIdx.x;
  const int wg = (bid & 7) * 32 + (bid >> 3);
  const int bx = wg & 15, by = wg >> 4;  // nbx = 3072/192 = 16
  const int bm = by << 8, bn = bx * 192;

  // Staging: thread t covers row srow (8 threads/row, 128B), pre-swizzled col.
  const int srow = t >> 3;                        // 0..63 per call
  const int scol = ((t & 7) ^ (srow & 7)) << 3;   // logical k-chunk, pre-swizzled
  const ushort* ag = A + (size_t)(bm + srow) * K + scol;
  const ushort* bg = Bw + (size_t)(bn + srow) * K + scol;
  const size_t rskip = (size_t)64 * K;

  f32x4 acc[8][3];
  const f32x4 z = {0.f, 0.f, 0.f, 0.f};
#pragma unroll
  for (int i = 0; i < 8; ++i)
#pragma unroll
    for (int j = 0; j < 3; ++j) acc[i][j] = z;

  const int aBase = (wm2 * 128 + l16) * 64;  // + mi*1024
  const int bBase = (wn4 * 48 + l16) * 64;   // + nj*1024
  const int cx = l16 & 7;

#define SG_A(bi, kt, c) \
  glds16(ag + (size_t)(c) * rskip + ((kt) << 6), &As[bi][(c)*4096 + wid * 512])
#define SG_B(bi, kt, c) \
  glds16(bg + (size_t)(c) * rskip + ((kt) << 6), &Bs[bi][(c)*4096 + wid * 512])
#define RD_A(bi, mi, kc) \
  (*(const bf16x8*)&As[bi][aBase + (mi)*1024 + ((((kc)*4 + quad) ^ cx) << 3)])
#define RD_B(bi, nj, kc) \
  (*(const bf16x8*)&Bs[bi][bBase + (nj)*1024 + ((((kc)*4 + quad) ^ cx) << 3)])

  // Prologue: tile 0 -> buf 0.
  SG_A(0, 0, 0); SG_A(0, 0, 1); SG_A(0, 0, 2); SG_A(0, 0, 3);
  SG_B(0, 0, 0); SG_B(0, 0, 1); SG_B(0, 0, 2);
  asm volatile("s_waitcnt vmcnt(0)" ::: "memory");
  __builtin_amdgcn_s_barrier();

  for (int i = 0; i < 16; ++i) {
    const int rb = i & 1, sb = rb ^ 1;
    if (i < 15) {  // stage tile i+1 (issue early; latency hides under compute)
      SG_A(sb, i + 1, 0); SG_A(sb, i + 1, 1); SG_A(sb, i + 1, 2); SG_A(sb, i + 1, 3);
      SG_B(sb, i + 1, 0); SG_B(sb, i + 1, 1); SG_B(sb, i + 1, 2);
    }
    bf16x8 bf[3][2];
#pragma unroll
    for (int nj = 0; nj < 3; ++nj) {
      bf[nj][0] = RD_B(rb, nj, 0);
      bf[nj][1] = RD_B(rb, nj, 1);
    }
    __builtin_amdgcn_s_setprio(1);
#pragma unroll
    for (int mp = 0; mp < 4; ++mp) {
      bf16x8 a00 = RD_A(rb, mp * 2, 0), a01 = RD_A(rb, mp * 2, 1);
      bf16x8 a10 = RD_A(rb, mp * 2 + 1, 0), a11 = RD_A(rb, mp * 2 + 1, 1);
#pragma unroll
      for (int nj = 0; nj < 3; ++nj) {
        acc[mp * 2][nj] = __builtin_amdgcn_mfma_f32_16x16x32_bf16(a00, bf[nj][0], acc[mp * 2][nj], 0, 0, 0);
        acc[mp * 2][nj] = __builtin_amdgcn_mfma_f32_16x16x32_bf16(a01, bf[nj][1], acc[mp * 2][nj], 0, 0, 0);
        acc[mp * 2 + 1][nj] = __builtin_amdgcn_mfma_f32_16x16x32_bf16(a10, bf[nj][0], acc[mp * 2 + 1][nj], 0, 0, 0);
        acc[mp * 2 + 1][nj] = __builtin_amdgcn_mfma_f32_16x16x32_bf16(a11, bf[nj][1], acc[mp * 2 + 1][nj], 0, 0, 0);
      }
    }
    __builtin_amdgcn_s_setprio(0);
    if (i < 15) {  // single sync point per K-tile: drain then swap
      asm volatile("s_waitcnt vmcnt(0)" ::: "memory");
      __builtin_amdgcn_s_barrier();
    }
  }

#undef SG_A
#undef SG_B
#undef RD_A
#undef RD_B

#pragma unroll
  for (int mi = 0; mi < 8; ++mi)
#pragma unroll
    for (int nj = 0; nj < 3; ++nj) {
      const int col = bn + wn4 * 48 + nj * 16 + l16;
      const float bv = bias[col];
      const float sc = ((col >> 10) == 1) ? 0.125f : 1.f;
#pragma unroll
      for (int r = 0; r < 4; ++r) {
        const int row = bm + wm2 * 128 + mi * 16 + quad * 4 + r;
        Cout[(size_t)row * N + col] = f2bf((acc[mi][nj][r] + bv) * sc);
      }
    }
}

// C = A[M,K]*Bw[N,K]^T + bias ; 128x128x32 tiles, identity staging.
// (R0-proven m97 structure, 596 TF at K=1024; used for the out projection.)
template <bool OUT_BF16, bool KSCALE>
__global__ __launch_bounds__(256) void gemm_bt(const ushort* __restrict__ A,
                                               const ushort* __restrict__ Bw,
                                               const float* __restrict__ bias,
                                               void* __restrict__ Cout,
                                               int M, int N, int K) {
  __shared__ ushort As[128 * 32];
  __shared__ ushort Bs[128 * 32];
  const int t = threadIdx.x;
  const int wid = t >> 6, lane = t & 63;
  const int quad = lane >> 4, l16 = lane & 15;
  const int bm = blockIdx.y * 128, bn = blockIdx.x * 128;
  const int wm = (wid >> 1) * 64, wn = (wid & 1) * 64;

  f32x4 acc[4][4];
  const f32x4 z = {0.f, 0.f, 0.f, 0.f};
#pragma unroll
  for (int i = 0; i < 4; ++i)
#pragma unroll
    for (int j = 0; j < 4; ++j) acc[i][j] = z;

  const ushort* ag = A + (size_t)(bm + (t >> 2)) * K + ((t & 3) * 8);
  const ushort* bg = Bw + (size_t)(bn + (t >> 2)) * K + ((t & 3) * 8);
  ushort* asl = As + wid * 512;
  ushort* bsl = Bs + wid * 512;
  const size_t rowskip = (size_t)64 * K;

  for (int k0 = 0; k0 < K; k0 += 32) {
    glds16(ag + k0, asl);
    glds16(ag + k0 + rowskip, asl + 2048);
    glds16(bg + k0, bsl);
    glds16(bg + k0 + rowskip, bsl + 2048);
    __syncthreads();
    bf16x8 af[4], bf[4];
#pragma unroll
    for (int i = 0; i < 4; ++i) {
      af[i] = *(const bf16x8*)(As + (wm + i * 16 + l16) * 32 + quad * 8);
      bf[i] = *(const bf16x8*)(Bs + (wn + i * 16 + l16) * 32 + quad * 8);
    }
#pragma unroll
    for (int i = 0; i < 4; ++i)
#pragma unroll
      for (int j = 0; j < 4; ++j)
        acc[i][j] = __builtin_amdgcn_mfma_f32_16x16x32_bf16(af[i], bf[j], acc[i][j], 0, 0, 0);
    __syncthreads();
  }

#pragma unroll
  for (int i = 0; i < 4; ++i)
#pragma unroll
    for (int j = 0; j < 4; ++j) {
      const int col = bn + wn + j * 16 + l16;
      const float bv = bias[col];
      float sc = 1.f;
      if (KSCALE) sc = ((col >> 10) == 1) ? 0.125f : 1.f;
#pragma unroll
      for (int r = 0; r < 4; ++r) {
        const int row = bm + wm + i * 16 + quad * 4 + r;
        const float v = (acc[i][j][r] + bv) * sc;
        if (OUT_BF16)
          ((ushort*)Cout)[(size_t)row * N + col] = f2bf(v);
        else
          ((float*)Cout)[(size_t)row * N + col] = v;
      }
    }
}

// Per-(bh,chunk) KV sums via MFMA: mlocT[bh][c][e][f] = sum_s v[s][e]*k[s][f].
__global__ __launch_bounds__(256) void kv_local(const ushort* __restrict__ qkv,
                                                float* __restrict__ mlocT) {
  const int c = blockIdx.x, bh = blockIdx.y;
  const int b = bh >> 4, hd = bh & 15;
  const int t = threadIdx.x;
  const int wid = t >> 6, lane = t & 63;
  const int quad = lane >> 4, l16 = lane & 15;
  __shared__ ushort kT[64 * 136];  // [f:64][s:128] pad 8
  __shared__ ushort vT[64 * 136];  // [e:64][s:128] pad 8

  {
    const int row = t & 127;
    const int isv = t >> 7;
    const ushort* g = qkv + (size_t)(b * 2048 + c * 128 + row) * 3072 +
                      1024 + isv * 1024 + hd * 64;
    ushort tmp[64];
#pragma unroll
    for (int q = 0; q < 8; ++q) *(uint4*)(tmp + q * 8) = *(const uint4*)(g + q * 8);
    ushort* dst = isv ? vT : kT;
#pragma unroll
    for (int j = 0; j < 64; ++j) dst[j * 136 + row] = tmp[j];
  }
  __syncthreads();

  const f32x4 z = {0.f, 0.f, 0.f, 0.f};
  f32x4 acc[4];
#pragma unroll
  for (int ct = 0; ct < 4; ++ct) acc[ct] = z;
#pragma unroll
  for (int kc = 0; kc < 4; ++kc) {
    bf16x8 afr = *(const bf16x8*)(vT + (wid * 16 + l16) * 136 + kc * 32 + quad * 8);
#pragma unroll
    for (int ct = 0; ct < 4; ++ct) {
      bf16x8 bfr = *(const bf16x8*)(kT + (ct * 16 + l16) * 136 + kc * 32 + quad * 8);
      acc[ct] = __builtin_amdgcn_mfma_f32_16x16x32_bf16(afr, bfr, acc[ct], 0, 0, 0);
    }
  }

  float* outp = mlocT + ((size_t)bh * 16 + c) * 4096;
#pragma unroll
  for (int ct = 0; ct < 4; ++ct)
#pragma unroll
    for (int r = 0; r < 4; ++r)
      outp[(wid * 16 + quad * 4 + r) * 64 + ct * 16 + l16] = acc[ct][r];
}

// Exclusive prefix over chunks, parallel over 4096 (e,f) entries per bh.
__global__ __launch_bounds__(256) void kv_prefix(const float* __restrict__ mlocT,
                                                 ushort* __restrict__ statesT) {
  const int slice = blockIdx.x, bh = blockIdx.y;
  const int eidx = slice * 256 + threadIdx.x;
  float run = 0.f;
  for (int c = 0; c < 16; ++c) {
    const size_t idx = ((size_t)bh * 16 + c) * 4096 + eidx;
    statesT[idx] = f2bf(run);
    run += mlocT[idx];
  }
}

// Per-(bh,chunk): P = tril(Q K^T) ; Y = P V + Q S_prefix (state from statesT).
__global__ __launch_bounds__(256) void attn_chunk(const ushort* __restrict__ qkv,
                                                  const ushort* __restrict__ statesT,
                                                  ushort* __restrict__ yb) {
  const int c = blockIdx.x, bh = blockIdx.y;
  const int b = bh >> 4, hd = bh & 15;
  const int l0 = c * 128;
  const int t = threadIdx.x;
  const int wid = t >> 6, lane = t & 63;
  const int quad = lane >> 4, l16 = lane & 15;

  __shared__ ushort P[16384];  // [row][16B chunks] XOR-swizzled by row&7
  __shared__ ushort U[16384];
  ushort* Qs = U;              // [row:128][64] chunk^(row&7)
  ushort* Ks = U + 8192;
  ushort* vT = U;              // phase2: [e:64][s:128] stride 136
  ushort* sT = U + 8704;       // phase2: [e:64][f:64]  stride 72

  {  // zero P
    uint4 zz; zz.x = zz.y = zz.z = zz.w = 0u;
    uint4* p4 = (uint4*)P;
#pragma unroll
    for (int i = 0; i < 8; ++i) p4[i * 256 + t] = zz;
  }
  {  // stage Q,K swizzled
    const int kcs = ((lane & 7) ^ (lane >> 3)) * 8;
    const ushort* qg = qkv + (size_t)(b * 2048 + l0 + (t >> 3)) * 3072 + hd * 64 + kcs;
    ushort* ql = Qs + wid * 512;
    ushort* kl = Ks + wid * 512;
#pragma unroll
    for (int h2 = 0; h2 < 4; ++h2) {
      glds16(qg + (size_t)h2 * 32 * 3072, ql + h2 * 2048);
      glds16(qg + (size_t)h2 * 32 * 3072 + 1024, kl + h2 * 2048);
    }
  }
  __syncthreads();

  bf16x8 qf[2][2];
#pragma unroll
  for (int i = 0; i < 2; ++i)
#pragma unroll
    for (int kc = 0; kc < 2; ++kc)
      qf[i][kc] = *(const bf16x8*)(Qs + ((wid * 2 + i) * 16 + l16) * 64 +
                                   (((kc * 4 + quad) ^ (l16 & 7)) * 8));

  const f32x4 z4 = {0.f, 0.f, 0.f, 0.f};
  f32x4 pacc[2][8];
#pragma unroll
  for (int i = 0; i < 2; ++i)
#pragma unroll
    for (int j = 0; j < 8; ++j) pacc[i][j] = z4;

#pragma unroll
  for (int i = 0; i < 2; ++i) {
    const int rt = wid * 2 + i;
#pragma unroll
    for (int tj = 0; tj < 8; ++tj) {
      if (tj <= rt) {
#pragma unroll
        for (int kc = 0; kc < 2; ++kc) {
          bf16x8 kfr = *(const bf16x8*)(Ks + (tj * 16 + l16) * 64 +
                                        (((kc * 4 + quad) ^ (l16 & 7)) * 8));
          pacc[i][tj] = __builtin_amdgcn_mfma_f32_16x16x32_bf16(qf[i][kc], kfr, pacc[i][tj], 0, 0, 0);
        }
      }
    }
  }
  __syncthreads();

#pragma unroll
  for (int i = 0; i < 2; ++i) {
    const int rt = wid * 2 + i;
#pragma unroll
    for (int tj = 0; tj < 8; ++tj) {
      if (tj <= rt) {
#pragma unroll
        for (int r = 0; r < 4; ++r) {
          const int row = rt * 16 + quad * 4 + r;
          const int scol = tj * 16 + l16;
          const float v = (scol <= row) ? pacc[i][tj][r] : 0.f;
          P[row * 128 + (((scol >> 3) ^ (row & 7)) * 8) + (scol & 7)] = f2bf(v);
        }
      }
    }
  }
  {  // stage V transposed: vT[e][s], stride 136
    const int sstep = t >> 1, eb = (t & 1) * 32;
    const ushort* vg = qkv + (size_t)(b * 2048 + l0 + sstep) * 3072 + 2048 + hd * 64 + eb;
    ushort tmp[32];
    *(uint4*)(tmp + 0)  = *(const uint4*)(vg + 0);
    *(uint4*)(tmp + 8)  = *(const uint4*)(vg + 8);
    *(uint4*)(tmp + 16) = *(const uint4*)(vg + 16);
    *(uint4*)(tmp + 24) = *(const uint4*)(vg + 24);
#pragma unroll
    for (int j = 0; j < 32; ++j) vT[(eb + j) * 136 + sstep] = tmp[j];
  }
  {  // stage state: 2 coalesced uint4 per thread -> sT stride 72
    const ushort* sg = statesT + ((size_t)bh * 16 + c) * 4096;
#pragma unroll
    for (int h = 0; h < 2; ++h) {
      const int cc = h * 256 + t;
      uint4 d = *(const uint4*)(sg + cc * 8);
      *(uint4*)(sT + (cc >> 3) * 72 + (cc & 7) * 8) = d;
    }
  }
  __syncthreads();

  f32x4 yacc[2][4];
#pragma unroll
  for (int i = 0; i < 2; ++i)
#pragma unroll
    for (int j = 0; j < 4; ++j) yacc[i][j] = z4;

#pragma unroll
  for (int i = 0; i < 2; ++i) {
    const int rt = wid * 2 + i;
    const int kcmax = rt >> 1;
#pragma unroll
    for (int kc = 0; kc < 4; ++kc) {
      if (kc <= kcmax) {
        const int prow = rt * 16 + l16;
        bf16x8 pf;
        *(uint4*)&pf = *(const uint4*)(P + prow * 128 + (((kc * 4 + quad) ^ (prow & 7)) * 8));
#pragma unroll
        for (int ct = 0; ct < 4; ++ct) {
          bf16x8 vf = *(const bf16x8*)(vT + (ct * 16 + l16) * 136 + kc * 32 + quad * 8);
          yacc[i][ct] = __builtin_amdgcn_mfma_f32_16x16x32_bf16(pf, vf, yacc[i][ct], 0, 0, 0);
        }
      }
    }
#pragma unroll
    for (int kc = 0; kc < 2; ++kc) {
#pragma unroll
      for (int ct = 0; ct < 4; ++ct) {
        bf16x8 sf = *(const bf16x8*)(sT + (ct * 16 + l16) * 72 + kc * 32 + quad * 8);
        yacc[i][ct] = __builtin_amdgcn_mfma_f32_16x16x32_bf16(qf[i][kc], sf, yacc[i][ct], 0, 0, 0);
      }
    }
  }

#pragma unroll
  for (int i = 0; i < 2; ++i) {
    const int rt = wid * 2 + i;
#pragma unroll
    for (int ct = 0; ct < 4; ++ct) {
#pragma unroll
      for (int r = 0; r < 4; ++r) {
        const int row = rt * 16 + quad * 4 + r;
        const int e = ct * 16 + l16;
        yb[(size_t)(b * 2048 + l0 + row) * 1024 + hd * 64 + e] = f2bf(yacc[i][ct][r]);
      }
    }
  }
}

extern "C" void kernel_launch(void* const* d_in, const int* in_sizes, int n_in,
                              void* d_out, int out_size, void* d_ws, size_t ws_size,
                              hipStream_t stream) {
  const float* x  = (const float*)d_in[0];
  const float* Ww = (const float*)d_in[1];
  const float* Wb = (const float*)d_in[2];
  const float* Ow = (const float*)d_in[3];
  const float* Ob = (const float*)d_in[4];
  float* out = (float*)d_out;

  char* ws = (char*)d_ws;
  ushort* xb      = (ushort*)(ws);
  ushort* wqkvb   = (ushort*)(ws + (size_t)8  * 1024 * 1024);
  ushort* outwb   = (ushort*)(ws + (size_t)14 * 1024 * 1024);
  ushort* qkvb    = (ushort*)(ws + (size_t)16 * 1024 * 1024);
  float*  mlocT   = (float*) (ws + (size_t)40 * 1024 * 1024);
  ushort* statesT = (ushort*)(ws + (size_t)48 * 1024 * 1024);
  ushort* yb      = (ushort*)(ws + (size_t)52 * 1024 * 1024);

  cvt_all<<<8192, 256, 0, stream>>>(x, Ww, Ow, xb, wqkvb, outwb);
  // 256x192 tiles: grid = (4096/256)*(3072/192) = 256 blocks, full chip.
  gemm_loose<<<dim3(256), 512, 0, stream>>>(xb, wqkvb, Wb, qkvb);
  kv_local<<<dim3(16, 32), 256, 0, stream>>>(qkvb, mlocT);
  kv_prefix<<<dim3(16, 32), 256, 0, stream>>>(mlocT, statesT);
  attn_chunk<<<dim3(16, 32), 256, 0, stream>>>(qkvb, statesT, yb);
  // Out projection on the R0-proven 128^2 structure: grid (1024/128, 4096/128).
  gemm_bt<false, false><<<dim3(8, 32), 256, 0, stream>>>(yb, outwb, Ob, out, 4096, 1024, 1024);
}

// Round 4
// 161.579 us; speedup vs baseline: 1.1846x; 1.0136x over previous
//
#include <hip/hip_runtime.h>

// LinearAttention: B=2, L=2048, D=1024, H=16, d=64.
// cvt_all ; QKV GEMM (R9: faithful m201 8-phase, counted vmcnt(6)) ; kv_local ;
// kv_prefix ; attn_chunk ; gemm_out64.
// R8 post-mortem: all drain-to-0-per-tile schedules plateau at ~40us (m218's
// "drain0 == 1-phase" null). R9 ports the verified m201 schedule: per phase
// {ds-read quadrant ; stage 1 half-panel ; bar ; lgkmcnt(0) ; 16 MFMA ; bar},
// vmcnt(6) ONLY at group boundaries (3 half-panels of tiles t+1/t+2 stay in
// flight across barriers). Region-death order (B@g1, A0@g2, A1@g4) makes the
// staggered staging write-after-read safe; every glds has >=4 phases of
// latency cover. vmcnt(0) only at the NT-2 boundary.

#define DEV __device__ __forceinline__

typedef __attribute__((ext_vector_type(8))) short bf16x8;
typedef __attribute__((ext_vector_type(4))) float f32x4;

DEV ushort f2bf(float f) {
  union { float f; unsigned u; } v; v.f = f;
  unsigned r = v.u + 0x7fffu + ((v.u >> 16) & 1u);
  return (ushort)(r >> 16);
}
DEV float bf2f(unsigned b) {
  union { unsigned u; float f; } v; v.u = (b & 0xffffu) << 16;
  return v.f;
}
DEV void glds16(const ushort* g, ushort* l) {
  __builtin_amdgcn_global_load_lds(
      (const __attribute__((address_space(1))) unsigned int*)g,
      (__attribute__((address_space(3))) unsigned int*)l, 16, 0, 0);
}

__global__ __launch_bounds__(256) void cvt_all(const float* __restrict__ x,
                                               const float* __restrict__ Ww,
                                               const float* __restrict__ Ow,
                                               ushort* __restrict__ xb,
                                               ushort* __restrict__ wqkvb,
                                               ushort* __restrict__ outwb) {
  int i = blockIdx.x * 256 + threadIdx.x;
  const float* src; ushort* dst; int off;
  if (i < 1048576)      { src = x;  dst = xb;    off = i; }
  else if (i < 1835008) { src = Ww; dst = wqkvb; off = i - 1048576; }
  else                  { src = Ow; dst = outwb; off = i - 1835008; }
  float4 v = ((const float4*)src)[off];
  ushort4 o;
  o.x = f2bf(v.x); o.y = f2bf(v.y); o.z = f2bf(v.z); o.w = f2bf(v.w);
  ((ushort4*)dst)[off] = o;
}

// ---------------------------------------------------------------------------
// QKV GEMM, hardcoded M=4096 N=3072 K=1024: qkv = xb * Wqkv^T + b, bf16 out,
// K-block (cols 1024..2047) scaled by 0.125. m201 8-phase template.
// BM=BN=256, BK=64, NT=16 K-tiles. Grid 12x16=192 blocks, 512 thr = 8 waves
// (2M x 4N); wave (wm2,wn4) owns M rows {wm2*64+[0,64), 128+wm2*64+[0,64)}
// x N cols wn4*64+[0,64)  -> acc 8x4 fragments.
// LDS 128 KiB: As[2][2][128x64] + Bs[2][2][128x64]  (dbuf x half).
// Group for tile t (buf rb=t&1), 4 phases, mi-pair quadrants:
//   g1: read 8 B-frags + A mi0,1 ; stage (t+1).A1 -> buf rb^1
//   g2: read A mi2,3             ; stage (t+2).B0 -> buf rb
//   g3: read A mi4,5             ; stage (t+2).B1 -> buf rb
//   g4: read A mi6,7             ; stage (t+2).A0 -> buf rb
//   boundary: vmcnt(6) (=g2..g4's 3 half-panels in flight), barrier.
// Death proof: B read only @g1; A0 (mi0-3, rows[0,128)) read @g1,g2;
// A1 (mi4-7) read @g3,g4 and staged only at next group's g1. Every staged
// region is dead >=1 phase before its glds issue; phase barriers order the
// issue after the last read block-wide. vmcnt(6) at boundary certifies tile
// t+1 fully landed (3 panels issued after its last panel stay outstanding).
// Swizzle (rule #21): glds source k-chunk pre-XORed by row&7, LDS linear;
// ds_read chunk (kc*4+quad)^(l16&7): 2-way bank alias only (free).
// ---------------------------------------------------------------------------
__global__ __launch_bounds__(512, 2) void gemm_8p(const ushort* __restrict__ A,
                                                  const ushort* __restrict__ Bw,
                                                  const float* __restrict__ bias,
                                                  ushort* __restrict__ Cout) {
  __shared__ __align__(16) ushort As[2][2][8192];  // [buf][half][128*64]
  __shared__ __align__(16) ushort Bs[2][2][8192];
  const int t = threadIdx.x;
  const int lane = t & 63, wid = t >> 6;
  const int quad = lane >> 4, l16 = lane & 15;
  const int wm2 = wid >> 2, wn4 = wid & 3;
  const int K = 1024, N = 3072;

  // T1: bijective XCD swizzle (192 % 8 == 0).
  const int bid = blockIdx.x;
  const int wg = (bid & 7) * 24 + (bid >> 3);
  const int bx = wg % 12, by = wg / 12;
  const int bm = by << 8, bn = bx << 8;

  // Staging source: thread t covers row (t>>3) of a 64-row call, pre-swizzled
  // 16B chunk (t&7)^((t>>3)&7).
  const int scol = ((t & 7) ^ ((t >> 3) & 7)) << 3;
  const ushort* ag = A + (size_t)(bm + (t >> 3)) * K + scol;
  const ushort* bg = Bw + (size_t)(bn + (t >> 3)) * K + scol;

  f32x4 acc[8][4];
  const f32x4 z = {0.f, 0.f, 0.f, 0.f};
#pragma unroll
  for (int i = 0; i < 8; ++i)
#pragma unroll
    for (int j = 0; j < 4; ++j) acc[i][j] = z;

  const int cx8 = l16 & 7;

  // Half-panel stage: 2 glds (rows h*128+[0,64) and h*128+[64,128)).
#define SG_A(bi, h, kt) \
  glds16(ag + (size_t)((h)*128) * K + ((kt) << 6), &As[bi][h][wid * 512]); \
  glds16(ag + (size_t)((h)*128 + 64) * K + ((kt) << 6), &As[bi][h][4096 + wid * 512])
#define SG_B(bi, h, kt) \
  glds16(bg + (size_t)((h)*128) * K + ((kt) << 6), &Bs[bi][h][wid * 512]); \
  glds16(bg + (size_t)((h)*128 + 64) * K + ((kt) << 6), &Bs[bi][h][4096 + wid * 512])
#define RD_A(bi, mi, kc) \
  (*(const bf16x8*)&As[bi][(mi) >> 2][(wm2 * 64 + ((mi)&3) * 16 + l16) * 64 + \
                                      ((((kc)*4 + quad) ^ cx8) << 3)])
#define RD_B(bi, nj, kc) \
  (*(const bf16x8*)&Bs[bi][wn4 >> 1][((wn4 & 1) * 64 + (nj)*16 + l16) * 64 + \
                                     ((((kc)*4 + quad) ^ cx8) << 3)])

  bf16x8 bfr[4][2];

#define PHASE(rbuf, m0, m1, STAGE_STMT, LAST) do { \
    bf16x8 pa00 = RD_A(rbuf, m0, 0), pa01 = RD_A(rbuf, m0, 1); \
    bf16x8 pa10 = RD_A(rbuf, m1, 0), pa11 = RD_A(rbuf, m1, 1); \
    STAGE_STMT; \
    __builtin_amdgcn_s_barrier(); \
    asm volatile("s_waitcnt lgkmcnt(0)" ::: "memory"); \
    __builtin_amdgcn_s_setprio(1); \
    _Pragma("unroll") \
    for (int nj = 0; nj < 4; ++nj) { \
      acc[m0][nj] = __builtin_amdgcn_mfma_f32_16x16x32_bf16(pa00, bfr[nj][0], acc[m0][nj], 0, 0, 0); \
      acc[m0][nj] = __builtin_amdgcn_mfma_f32_16x16x32_bf16(pa01, bfr[nj][1], acc[m0][nj], 0, 0, 0); \
      acc[m1][nj] = __builtin_amdgcn_mfma_f32_16x16x32_bf16(pa10, bfr[nj][0], acc[m1][nj], 0, 0, 0); \
      acc[m1][nj] = __builtin_amdgcn_mfma_f32_16x16x32_bf16(pa11, bfr[nj][1], acc[m1][nj], 0, 0, 0); \
    } \
    __builtin_amdgcn_s_setprio(0); \
    if (!(LAST)) __builtin_amdgcn_s_barrier(); \
  } while (0)

#define GROUP(rbuf, kt) do { \
    _Pragma("unroll") \
    for (int nj = 0; nj < 4; ++nj) { \
      bfr[nj][0] = RD_B(rbuf, nj, 0); \
      bfr[nj][1] = RD_B(rbuf, nj, 1); \
    } \
    PHASE(rbuf, 0, 1, if ((kt) + 1 < 16) { SG_A(1 - (rbuf), 1, (kt) + 1); }, 0); \
    PHASE(rbuf, 2, 3, if ((kt) + 2 < 16) { SG_B(rbuf, 0, (kt) + 2); }, 0); \
    PHASE(rbuf, 4, 5, if ((kt) + 2 < 16) { SG_B(rbuf, 1, (kt) + 2); }, 0); \
    PHASE(rbuf, 6, 7, if ((kt) + 2 < 16) { SG_A(rbuf, 0, (kt) + 2); }, 1); \
    if ((kt) < 15) { \
      if ((kt) == 14) asm volatile("s_waitcnt vmcnt(0)" ::: "memory"); \
      else            asm volatile("s_waitcnt vmcnt(6)" ::: "memory"); \
      __builtin_amdgcn_s_barrier(); \
    } \
  } while (0)

  // Prologue: tile0 (8 loads) -> buf0 ; tile1 B0,B1,A0 (6 loads) -> buf1.
  SG_B(0, 0, 0); SG_B(0, 1, 0); SG_A(0, 0, 0); SG_A(0, 1, 0);
  SG_B(1, 0, 1); SG_B(1, 1, 1); SG_A(1, 0, 1);
  asm volatile("s_waitcnt vmcnt(6)" ::: "memory");
  __builtin_amdgcn_s_barrier();

  for (int kt2 = 0; kt2 < 16; kt2 += 2) {
    GROUP(0, kt2);
    GROUP(1, kt2 + 1);
  }

#undef GROUP
#undef PHASE
#undef RD_A
#undef RD_B
#undef SG_A
#undef SG_B

#pragma unroll
  for (int mi = 0; mi < 8; ++mi)
#pragma unroll
    for (int nj = 0; nj < 4; ++nj) {
      const int col = bn + wn4 * 64 + nj * 16 + l16;
      const float bv = bias[col];
      const float sc = ((col >> 10) == 1) ? 0.125f : 1.f;
#pragma unroll
      for (int r = 0; r < 4; ++r) {
        const int row = bm + (mi >> 2) * 128 + wm2 * 64 + (mi & 3) * 16 + quad * 4 + r;
        Cout[(size_t)row * N + col] = f2bf((acc[mi][nj][r] + bv) * sc);
      }
    }
}

// Out projection: BM=64, BN=128, BK=32 -> 512 blocks (2/CU), identity staging.
__global__ __launch_bounds__(256) void gemm_out64(const ushort* __restrict__ A,
                                                  const ushort* __restrict__ Bw,
                                                  const float* __restrict__ bias,
                                                  float* __restrict__ C,
                                                  int M, int N, int K) {
  __shared__ ushort As[64 * 32];
  __shared__ ushort Bs[128 * 32];
  const int t = threadIdx.x;
  const int wid = t >> 6, lane = t & 63;
  const int quad = lane >> 4, l16 = lane & 15;
  const int bm = blockIdx.y * 64, bn = blockIdx.x * 128;
  const int wn = wid * 32;

  f32x4 acc[4][2];
  const f32x4 z = {0.f, 0.f, 0.f, 0.f};
#pragma unroll
  for (int i = 0; i < 4; ++i) { acc[i][0] = z; acc[i][1] = z; }

  const ushort* ag = A + (size_t)(bm + (t >> 2)) * K + ((t & 3) * 8);
  const ushort* bg = Bw + (size_t)(bn + (t >> 2)) * K + ((t & 3) * 8);
  ushort* asl = As + wid * 512;
  ushort* bsl = Bs + wid * 512;
  const size_t rowskip = (size_t)64 * K;

  for (int k0 = 0; k0 < K; k0 += 32) {
    glds16(ag + k0, asl);
    glds16(bg + k0, bsl);
    glds16(bg + k0 + rowskip, bsl + 2048);
    __syncthreads();
    bf16x8 af[4], bf[2];
#pragma unroll
    for (int i = 0; i < 4; ++i)
      af[i] = *(const bf16x8*)(As + (i * 16 + l16) * 32 + quad * 8);
#pragma unroll
    for (int j = 0; j < 2; ++j)
      bf[j] = *(const bf16x8*)(Bs + (wn + j * 16 + l16) * 32 + quad * 8);
#pragma unroll
    for (int i = 0; i < 4; ++i)
#pragma unroll
      for (int j = 0; j < 2; ++j)
        acc[i][j] = __builtin_amdgcn_mfma_f32_16x16x32_bf16(af[i], bf[j], acc[i][j], 0, 0, 0);
    __syncthreads();
  }

#pragma unroll
  for (int i = 0; i < 4; ++i)
#pragma unroll
    for (int j = 0; j < 2; ++j) {
      const int col = bn + wn + j * 16 + l16;
      const float bv = bias[col];
#pragma unroll
      for (int r = 0; r < 4; ++r) {
        const int row = bm + i * 16 + quad * 4 + r;
        C[(size_t)row * N + col] = acc[i][j][r] + bv;
      }
    }
}

// Per-(bh,chunk) KV sums via MFMA: mlocT[bh][c][e][f] = sum_s v[s][e]*k[s][f].
__global__ __launch_bounds__(256) void kv_local(const ushort* __restrict__ qkv,
                                                float* __restrict__ mlocT) {
  const int c = blockIdx.x, bh = blockIdx.y;
  const int b = bh >> 4, hd = bh & 15;
  const int t = threadIdx.x;
  const int wid = t >> 6, lane = t & 63;
  const int quad = lane >> 4, l16 = lane & 15;
  __shared__ ushort kT[64 * 136];  // [f:64][s:128] pad 8
  __shared__ ushort vT[64 * 136];  // [e:64][s:128] pad 8

  {
    const int row = t & 127;
    const int isv = t >> 7;
    const ushort* g = qkv + (size_t)(b * 2048 + c * 128 + row) * 3072 +
                      1024 + isv * 1024 + hd * 64;
    ushort tmp[64];
#pragma unroll
    for (int q = 0; q < 8; ++q) *(uint4*)(tmp + q * 8) = *(const uint4*)(g + q * 8);
    ushort* dst = isv ? vT : kT;
#pragma unroll
    for (int j = 0; j < 64; ++j) dst[j * 136 + row] = tmp[j];
  }
  __syncthreads();

  const f32x4 z = {0.f, 0.f, 0.f, 0.f};
  f32x4 acc[4];
#pragma unroll
  for (int ct = 0; ct < 4; ++ct) acc[ct] = z;
#pragma unroll
  for (int kc = 0; kc < 4; ++kc) {
    bf16x8 afr = *(const bf16x8*)(vT + (wid * 16 + l16) * 136 + kc * 32 + quad * 8);
#pragma unroll
    for (int ct = 0; ct < 4; ++ct) {
      bf16x8 bfr = *(const bf16x8*)(kT + (ct * 16 + l16) * 136 + kc * 32 + quad * 8);
      acc[ct] = __builtin_amdgcn_mfma_f32_16x16x32_bf16(afr, bfr, acc[ct], 0, 0, 0);
    }
  }

  float* outp = mlocT + ((size_t)bh * 16 + c) * 4096;
#pragma unroll
  for (int ct = 0; ct < 4; ++ct)
#pragma unroll
    for (int r = 0; r < 4; ++r)
      outp[(wid * 16 + quad * 4 + r) * 64 + ct * 16 + l16] = acc[ct][r];
}

// Exclusive prefix over chunks, parallel over 4096 (e,f) entries per bh.
__global__ __launch_bounds__(256) void kv_prefix(const float* __restrict__ mlocT,
                                                 ushort* __restrict__ statesT) {
  const int slice = blockIdx.x, bh = blockIdx.y;
  const int eidx = slice * 256 + threadIdx.x;
  float run = 0.f;
  for (int c = 0; c < 16; ++c) {
    const size_t idx = ((size_t)bh * 16 + c) * 4096 + eidx;
    statesT[idx] = f2bf(run);
    run += mlocT[idx];
  }
}

// Per-(bh,chunk): P = tril(Q K^T) ; Y = P V + Q S_prefix (state from statesT).
__global__ __launch_bounds__(256) void attn_chunk(const ushort* __restrict__ qkv,
                                                  const ushort* __restrict__ statesT,
                                                  ushort* __restrict__ yb) {
  const int c = blockIdx.x, bh = blockIdx.y;
  const int b = bh >> 4, hd = bh & 15;
  const int l0 = c * 128;
  const int t = threadIdx.x;
  const int wid = t >> 6, lane = t & 63;
  const int quad = lane >> 4, l16 = lane & 15;

  __shared__ ushort P[16384];  // [row][16B chunks] XOR-swizzled by row&7
  __shared__ ushort U[16384];
  ushort* Qs = U;              // [row:128][64] chunk^(row&7)
  ushort* Ks = U + 8192;
  ushort* vT = U;              // phase2: [e:64][s:128] stride 136
  ushort* sT = U + 8704;       // phase2: [e:64][f:64]  stride 72

  {  // zero P
    uint4 zz; zz.x = zz.y = zz.z = zz.w = 0u;
    uint4* p4 = (uint4*)P;
#pragma unroll
    for (int i = 0; i < 8; ++i) p4[i * 256 + t] = zz;
  }
  {  // stage Q,K swizzled
    const int kcs = ((lane & 7) ^ (lane >> 3)) * 8;
    const ushort* qg = qkv + (size_t)(b * 2048 + l0 + (t >> 3)) * 3072 + hd * 64 + kcs;
    ushort* ql = Qs + wid * 512;
    ushort* kl = Ks + wid * 512;
#pragma unroll
    for (int h2 = 0; h2 < 4; ++h2) {
      glds16(qg + (size_t)h2 * 32 * 3072, ql + h2 * 2048);
      glds16(qg + (size_t)h2 * 32 * 3072 + 1024, kl + h2 * 2048);
    }
  }
  __syncthreads();

  bf16x8 qf[2][2];
#pragma unroll
  for (int i = 0; i < 2; ++i)
#pragma unroll
    for (int kc = 0; kc < 2; ++kc)
      qf[i][kc] = *(const bf16x8*)(Qs + ((wid * 2 + i) * 16 + l16) * 64 +
                                   (((kc * 4 + quad) ^ (l16 & 7)) * 8));

  const f32x4 z4 = {0.f, 0.f, 0.f, 0.f};
  f32x4 pacc[2][8];
#pragma unroll
  for (int i = 0; i < 2; ++i)
#pragma unroll
    for (int j = 0; j < 8; ++j) pacc[i][j] = z4;

#pragma unroll
  for (int i = 0; i < 2; ++i) {
    const int rt = wid * 2 + i;
#pragma unroll
    for (int tj = 0; tj < 8; ++tj) {
      if (tj <= rt) {
#pragma unroll
        for (int kc = 0; kc < 2; ++kc) {
          bf16x8 kfr = *(const bf16x8*)(Ks + (tj * 16 + l16) * 64 +
                                        (((kc * 4 + quad) ^ (l16 & 7)) * 8));
          pacc[i][tj] = __builtin_amdgcn_mfma_f32_16x16x32_bf16(qf[i][kc], kfr, pacc[i][tj], 0, 0, 0);
        }
      }
    }
  }
  __syncthreads();

#pragma unroll
  for (int i = 0; i < 2; ++i) {
    const int rt = wid * 2 + i;
#pragma unroll
    for (int tj = 0; tj < 8; ++tj) {
      if (tj <= rt) {
#pragma unroll
        for (int r = 0; r < 4; ++r) {
          const int row = rt * 16 + quad * 4 + r;
          const int scol = tj * 16 + l16;
          const float v = (scol <= row) ? pacc[i][tj][r] : 0.f;
          P[row * 128 + (((scol >> 3) ^ (row & 7)) * 8) + (scol & 7)] = f2bf(v);
        }
      }
    }
  }
  {  // stage V transposed: vT[e][s], stride 136
    const int sstep = t >> 1, eb = (t & 1) * 32;
    const ushort* vg = qkv + (size_t)(b * 2048 + l0 + sstep) * 3072 + 2048 + hd * 64 + eb;
    ushort tmp[32];
    *(uint4*)(tmp + 0)  = *(const uint4*)(vg + 0);
    *(uint4*)(tmp + 8)  = *(const uint4*)(vg + 8);
    *(uint4*)(tmp + 16) = *(const uint4*)(vg + 16);
    *(uint4*)(tmp + 24) = *(const uint4*)(vg + 24);
#pragma unroll
    for (int j = 0; j < 32; ++j) vT[(eb + j) * 136 + sstep] = tmp[j];
  }
  {  // stage state: 2 coalesced uint4 per thread -> sT stride 72
    const ushort* sg = statesT + ((size_t)bh * 16 + c) * 4096;
#pragma unroll
    for (int h = 0; h < 2; ++h) {
      const int cc = h * 256 + t;
      uint4 d = *(const uint4*)(sg + cc * 8);
      *(uint4*)(sT + (cc >> 3) * 72 + (cc & 7) * 8) = d;
    }
  }
  __syncthreads();

  f32x4 yacc[2][4];
#pragma unroll
  for (int i = 0; i < 2; ++i)
#pragma unroll
    for (int j = 0; j < 4; ++j) yacc[i][j] = z4;

#pragma unroll
  for (int i = 0; i < 2; ++i) {
    const int rt = wid * 2 + i;
    const int kcmax = rt >> 1;
#pragma unroll
    for (int kc = 0; kc < 4; ++kc) {
      if (kc <= kcmax) {
        const int prow = rt * 16 + l16;
        bf16x8 pf;
        *(uint4*)&pf = *(const uint4*)(P + prow * 128 + (((kc * 4 + quad) ^ (prow & 7)) * 8));
#pragma unroll
        for (int ct = 0; ct < 4; ++ct) {
          bf16x8 vf = *(const bf16x8*)(vT + (ct * 16 + l16) * 136 + kc * 32 + quad * 8);
          yacc[i][ct] = __builtin_amdgcn_mfma_f32_16x16x32_bf16(pf, vf, yacc[i][ct], 0, 0, 0);
        }
      }
    }
#pragma unroll
    for (int kc = 0; kc < 2; ++kc) {
#pragma unroll
      for (int ct = 0; ct < 4; ++ct) {
        bf16x8 sf = *(const bf16x8*)(sT + (ct * 16 + l16) * 72 + kc * 32 + quad * 8);
        yacc[i][ct] = __builtin_amdgcn_mfma_f32_16x16x32_bf16(qf[i][kc], sf, yacc[i][ct], 0, 0, 0);
      }
    }
  }

#pragma unroll
  for (int i = 0; i < 2; ++i) {
    const int rt = wid * 2 + i;
#pragma unroll
    for (int ct = 0; ct < 4; ++ct) {
#pragma unroll
      for (int r = 0; r < 4; ++r) {
        const int row = rt * 16 + quad * 4 + r;
        const int e = ct * 16 + l16;
        yb[(size_t)(b * 2048 + l0 + row) * 1024 + hd * 64 + e] = f2bf(yacc[i][ct][r]);
      }
    }
  }
}

extern "C" void kernel_launch(void* const* d_in, const int* in_sizes, int n_in,
                              void* d_out, int out_size, void* d_ws, size_t ws_size,
                              hipStream_t stream) {
  const float* x  = (const float*)d_in[0];
  const float* Ww = (const float*)d_in[1];
  const float* Wb = (const float*)d_in[2];
  const float* Ow = (const float*)d_in[3];
  const float* Ob = (const float*)d_in[4];
  float* out = (float*)d_out;

  char* ws = (char*)d_ws;
  ushort* xb      = (ushort*)(ws);
  ushort* wqkvb   = (ushort*)(ws + (size_t)8  * 1024 * 1024);
  ushort* outwb   = (ushort*)(ws + (size_t)14 * 1024 * 1024);
  ushort* qkvb    = (ushort*)(ws + (size_t)16 * 1024 * 1024);
  float*  mlocT   = (float*) (ws + (size_t)40 * 1024 * 1024);
  ushort* statesT = (ushort*)(ws + (size_t)48 * 1024 * 1024);
  ushort* yb      = (ushort*)(ws + (size_t)52 * 1024 * 1024);

  cvt_all<<<8192, 256, 0, stream>>>(x, Ww, Ow, xb, wqkvb, outwb);
  // 256^2 tiles: grid = (3072/256)*(4096/256) = 192 blocks (1D, XCD-swizzled).
  gemm_8p<<<dim3(192), 512, 0, stream>>>(xb, wqkvb, Wb, qkvb);
  kv_local<<<dim3(16, 32), 256, 0, stream>>>(qkvb, mlocT);
  kv_prefix<<<dim3(16, 32), 256, 0, stream>>>(mlocT, statesT);
  attn_chunk<<<dim3(16, 32), 256, 0, stream>>>(qkvb, statesT, yb);
  gemm_out64<<<dim3(8, 64), 256, 0, stream>>>(yb, outwb, Ob, out, 4096, 1024, 1024);
}

// Round 6
// 159.665 us; speedup vs baseline: 1.1988x; 1.0120x over previous
//
#include <hip/hip_runtime.h>

// LinearAttention: B=2, L=2048, D=1024, H=16, d=64.
// cvt_all ; QKV GEMM (R1-proven gemm_bt8 256^2 tile-dbuf) ; kv_local (R10:
// b32-packed transpose) ; kv_prefix ; attn_chunk (R10: causal load-balance
// rt={wid,7-wid} + b32-packed V transpose) ; gemm_out64.
// R11 = R10 resubmitted verbatim: round-5 bench died with an infra error
// ("MI355X container failed twice"), no kernel signal. Audit found no
// deadlock/OOB surface: packed-b32 transposes are aligned + bijective,
// {wid,7-wid} covers all 8 row-tiles, attn/kv sync via __syncthreads only,
// gemm_bt8 byte-identical to the R1 kernel that passed.
// R9 post-mortem: all fine-phased QKV schedules (m201 port 50us, quad-buf
// 72us) lose to loose structures (40-43us) at K=1024 / 1 block/CU -- QKV lane
// exhausted, reverted to the best-measured R1 kernel. R10 attacks the ~118us
// non-QKV pipeline: attn_chunk's old rt={2w,2w+1} mapping gave wave3 5x the
// causal work of wave0 with two full barriers waiting on it; {wid,7-wid}
// makes QK^T 9 units/wave and PV 20 MFMAs/wave uniform. Scalar b16 LDS
// transposes in kv_local/attn halved via row-pair-packed ds_write_b32.

#define DEV __device__ __forceinline__

typedef __attribute__((ext_vector_type(8))) short bf16x8;
typedef __attribute__((ext_vector_type(4))) float f32x4;

DEV ushort f2bf(float f) {
  union { float f; unsigned u; } v; v.f = f;
  unsigned r = v.u + 0x7fffu + ((v.u >> 16) & 1u);
  return (ushort)(r >> 16);
}
DEV float bf2f(unsigned b) {
  union { unsigned u; float f; } v; v.u = (b & 0xffffu) << 16;
  return v.f;
}
DEV void glds16(const ushort* g, ushort* l) {
  __builtin_amdgcn_global_load_lds(
      (const __attribute__((address_space(1))) unsigned int*)g,
      (__attribute__((address_space(3))) unsigned int*)l, 16, 0, 0);
}

__global__ __launch_bounds__(256) void cvt_all(const float* __restrict__ x,
                                               const float* __restrict__ Ww,
                                               const float* __restrict__ Ow,
                                               ushort* __restrict__ xb,
                                               ushort* __restrict__ wqkvb,
                                               ushort* __restrict__ outwb) {
  int i = blockIdx.x * 256 + threadIdx.x;
  const float* src; ushort* dst; int off;
  if (i < 1048576)      { src = x;  dst = xb;    off = i; }
  else if (i < 1835008) { src = Ww; dst = wqkvb; off = i - 1048576; }
  else                  { src = Ow; dst = outwb; off = i - 1835008; }
  float4 v = ((const float4*)src)[off];
  ushort4 o;
  o.x = f2bf(v.x); o.y = f2bf(v.y); o.z = f2bf(v.z); o.w = f2bf(v.w);
  ((ushort4*)dst)[off] = o;
}

// ---------------------------------------------------------------------------
// QKV GEMM (R1-proven): 256x256 tiles, BK=64 dbuf, 8 waves (2M x 4N),
// 4 phases/tile with raw barriers, vmcnt(0) twice per 8 phases, T2 swizzle
// (pre-swizzled global source + XOR ds_read), T1 XCD swizzle, T5 setprio.
// ---------------------------------------------------------------------------
template <bool OUT_BF16, bool KSCALE>
__global__ __launch_bounds__(512, 2) void gemm_bt8(const ushort* __restrict__ A,
                                                   const ushort* __restrict__ Bw,
                                                   const float* __restrict__ bias,
                                                   void* __restrict__ Cout,
                                                   int M, int N, int K) {
  __shared__ __align__(16) ushort As[2][16384];
  __shared__ __align__(16) ushort Bs[2][16384];
  const int t = threadIdx.x;
  const int lane = t & 63, wid = t >> 6;
  const int quad = lane >> 4, l16 = lane & 15;
  const int wm2 = wid >> 2, wn4 = wid & 3;

  const int nwg = gridDim.x;
  const int bid = blockIdx.x;
  const int wg = (bid & 7) * (nwg >> 3) + (bid >> 3);
  const int nbx = N >> 8;
  const int bx = wg % nbx, by = wg / nbx;
  const int bm = by << 8, bn = bx << 8;

  const int srow = t >> 3;
  const int scol = ((t & 7) ^ (srow & 7)) << 3;
  const ushort* ag = A + (size_t)(bm + srow) * K + scol;
  const ushort* bg = Bw + (size_t)(bn + srow) * K + scol;
  const int NT = K >> 6;

  f32x4 acc[8][4];
  const f32x4 z = {0.f, 0.f, 0.f, 0.f};
#pragma unroll
  for (int i = 0; i < 8; ++i)
#pragma unroll
    for (int j = 0; j < 4; ++j) acc[i][j] = z;

  const int aRow = wm2 * 128 + l16;
  const int bRow = wn4 * 64 + l16;
  const int cxor = l16 & 7;

#define SG_A(bufi, kt, h, j) \
  glds16(ag + (size_t)((h)*128 + (j)*64) * K + ((kt) << 6), \
         &As[bufi][(h)*8192 + (j)*4096 + wid * 512])
#define SG_B(bufi, kt, h, j) \
  glds16(bg + (size_t)((h)*128 + (j)*64) * K + ((kt) << 6), \
         &Bs[bufi][(h)*8192 + (j)*4096 + wid * 512])
#define RD_A(bufi, mi, kc) \
  (*(const bf16x8*)&As[bufi][(aRow + (mi)*16) * 64 + ((((kc)*4 + quad) ^ cxor) << 3)])
#define RD_B(bufi, nj, kc) \
  (*(const bf16x8*)&Bs[bufi][(bRow + (nj)*16) * 64 + ((((kc)*4 + quad) ^ cxor) << 3)])

  SG_A(0, 0, 0, 0); SG_A(0, 0, 0, 1); SG_A(0, 0, 1, 0); SG_A(0, 0, 1, 1);
  SG_B(0, 0, 0, 0); SG_B(0, 0, 0, 1); SG_B(0, 0, 1, 0); SG_B(0, 0, 1, 1);
  asm volatile("s_waitcnt vmcnt(0)" ::: "memory");
  __builtin_amdgcn_s_barrier();

  bf16x8 bf[4][2], af[2][2];

#define LOAD_AF(rb, mi0) \
  af[0][0] = RD_A(rb, (mi0), 0); af[0][1] = RD_A(rb, (mi0), 1); \
  af[1][0] = RD_A(rb, (mi0) + 1, 0); af[1][1] = RD_A(rb, (mi0) + 1, 1);

#define MFMA16(mi0) \
  __builtin_amdgcn_s_setprio(1); \
  _Pragma("unroll") \
  for (int nj = 0; nj < 4; ++nj) { \
    acc[(mi0)][nj] = __builtin_amdgcn_mfma_f32_16x16x32_bf16(af[0][0], bf[nj][0], acc[(mi0)][nj], 0, 0, 0); \
    acc[(mi0)][nj] = __builtin_amdgcn_mfma_f32_16x16x32_bf16(af[0][1], bf[nj][1], acc[(mi0)][nj], 0, 0, 0); \
    acc[(mi0) + 1][nj] = __builtin_amdgcn_mfma_f32_16x16x32_bf16(af[1][0], bf[nj][0], acc[(mi0) + 1][nj], 0, 0, 0); \
    acc[(mi0) + 1][nj] = __builtin_amdgcn_mfma_f32_16x16x32_bf16(af[1][1], bf[nj][1], acc[(mi0) + 1][nj], 0, 0, 0); \
  } \
  __builtin_amdgcn_s_setprio(0);

#define HALFSTEP(rb, sb, stTile, doSt) do { \
    if (doSt) { SG_A(sb, stTile, 0, 0); SG_A(sb, stTile, 0, 1); \
                SG_A(sb, stTile, 1, 0); SG_A(sb, stTile, 1, 1); } \
    _Pragma("unroll") \
    for (int nj = 0; nj < 4; ++nj) { bf[nj][0] = RD_B(rb, nj, 0); bf[nj][1] = RD_B(rb, nj, 1); } \
    LOAD_AF(rb, 0); \
    __builtin_amdgcn_s_barrier(); \
    MFMA16(0); \
    __builtin_amdgcn_s_barrier(); \
    if (doSt) { SG_B(sb, stTile, 0, 0); SG_B(sb, stTile, 0, 1); } \
    LOAD_AF(rb, 2); \
    __builtin_amdgcn_s_barrier(); \
    MFMA16(2); \
    __builtin_amdgcn_s_barrier(); \
    if (doSt) { SG_B(sb, stTile, 1, 0); SG_B(sb, stTile, 1, 1); } \
    LOAD_AF(rb, 4); \
    __builtin_amdgcn_s_barrier(); \
    MFMA16(4); \
    __builtin_amdgcn_s_barrier(); \
    LOAD_AF(rb, 6); \
    __builtin_amdgcn_s_barrier(); \
    MFMA16(6); \
    asm volatile("s_waitcnt vmcnt(0)" ::: "memory"); \
    __builtin_amdgcn_s_barrier(); \
  } while (0)

  const int half = NT >> 1;
  for (int i = 0; i < half; ++i) {
    HALFSTEP(0, 1, 2 * i + 1, true);
    HALFSTEP(1, 0, 2 * i + 2, (i < half - 1));
  }

#undef HALFSTEP
#undef MFMA16
#undef LOAD_AF
#undef RD_A
#undef RD_B
#undef SG_A
#undef SG_B

#pragma unroll
  for (int mi = 0; mi < 8; ++mi)
#pragma unroll
    for (int nj = 0; nj < 4; ++nj) {
      const int col = bn + wn4 * 64 + nj * 16 + l16;
      const float bv = bias[col];
      float sc = 1.f;
      if (KSCALE) sc = ((col >> 10) == 1) ? 0.125f : 1.f;
#pragma unroll
      for (int r = 0; r < 4; ++r) {
        const int row = bm + wm2 * 128 + mi * 16 + quad * 4 + r;
        const float v = (acc[mi][nj][r] + bv) * sc;
        if (OUT_BF16)
          ((ushort*)Cout)[(size_t)row * N + col] = f2bf(v);
        else
          ((float*)Cout)[(size_t)row * N + col] = v;
      }
    }
}

// Out projection: BM=64, BN=128, BK=32 -> 512 blocks (2/CU), identity staging.
__global__ __launch_bounds__(256) void gemm_out64(const ushort* __restrict__ A,
                                                  const ushort* __restrict__ Bw,
                                                  const float* __restrict__ bias,
                                                  float* __restrict__ C,
                                                  int M, int N, int K) {
  __shared__ ushort As[64 * 32];
  __shared__ ushort Bs[128 * 32];
  const int t = threadIdx.x;
  const int wid = t >> 6, lane = t & 63;
  const int quad = lane >> 4, l16 = lane & 15;
  const int bm = blockIdx.y * 64, bn = blockIdx.x * 128;
  const int wn = wid * 32;

  f32x4 acc[4][2];
  const f32x4 z = {0.f, 0.f, 0.f, 0.f};
#pragma unroll
  for (int i = 0; i < 4; ++i) { acc[i][0] = z; acc[i][1] = z; }

  const ushort* ag = A + (size_t)(bm + (t >> 2)) * K + ((t & 3) * 8);
  const ushort* bg = Bw + (size_t)(bn + (t >> 2)) * K + ((t & 3) * 8);
  ushort* asl = As + wid * 512;
  ushort* bsl = Bs + wid * 512;
  const size_t rowskip = (size_t)64 * K;

  for (int k0 = 0; k0 < K; k0 += 32) {
    glds16(ag + k0, asl);
    glds16(bg + k0, bsl);
    glds16(bg + k0 + rowskip, bsl + 2048);
    __syncthreads();
    bf16x8 af[4], bf[2];
#pragma unroll
    for (int i = 0; i < 4; ++i)
      af[i] = *(const bf16x8*)(As + (i * 16 + l16) * 32 + quad * 8);
#pragma unroll
    for (int j = 0; j < 2; ++j)
      bf[j] = *(const bf16x8*)(Bs + (wn + j * 16 + l16) * 32 + quad * 8);
#pragma unroll
    for (int i = 0; i < 4; ++i)
#pragma unroll
      for (int j = 0; j < 2; ++j)
        acc[i][j] = __builtin_amdgcn_mfma_f32_16x16x32_bf16(af[i], bf[j], acc[i][j], 0, 0, 0);
    __syncthreads();
  }

#pragma unroll
  for (int i = 0; i < 4; ++i)
#pragma unroll
    for (int j = 0; j < 2; ++j) {
      const int col = bn + wn + j * 16 + l16;
      const float bv = bias[col];
#pragma unroll
      for (int r = 0; r < 4; ++r) {
        const int row = bm + i * 16 + quad * 4 + r;
        C[(size_t)row * N + col] = acc[i][j][r] + bv;
      }
    }
}

// Per-(bh,chunk) KV sums via MFMA: mlocT[bh][c][e][f] = sum_s v[s][e]*k[s][f].
// R10: transpose staging packs row-pairs into ds_write_b32 (32 writes vs 64).
__global__ __launch_bounds__(256) void kv_local(const ushort* __restrict__ qkv,
                                                float* __restrict__ mlocT) {
  const int c = blockIdx.x, bh = blockIdx.y;
  const int b = bh >> 4, hd = bh & 15;
  const int t = threadIdx.x;
  const int wid = t >> 6, lane = t & 63;
  const int quad = lane >> 4, l16 = lane & 15;
  __shared__ ushort kT[64 * 136];  // [f:64][s:128] pad 8
  __shared__ ushort vT[64 * 136];  // [e:64][s:128] pad 8

  {
    const int x = t & 127;
    const int isv = t >> 7;
    const int rp = x >> 1;          // rows 2rp, 2rp+1
    const int half = (x & 1) * 32;  // j-range half..half+31
    const ushort* g0 = qkv + (size_t)(b * 2048 + c * 128 + 2 * rp) * 3072 +
                       1024 + isv * 1024 + hd * 64 + half;
    const ushort* g1 = g0 + 3072;
    ushort ta[32], tb[32];
#pragma unroll
    for (int q = 0; q < 4; ++q) {
      *(uint4*)(ta + q * 8) = *(const uint4*)(g0 + q * 8);
      *(uint4*)(tb + q * 8) = *(const uint4*)(g1 + q * 8);
    }
    ushort* dst = isv ? vT : kT;
#pragma unroll
    for (int j = 0; j < 32; ++j) {
      unsigned pk = (unsigned)ta[j] | ((unsigned)tb[j] << 16);
      *(unsigned*)(dst + (half + j) * 136 + 2 * rp) = pk;
    }
  }
  __syncthreads();

  const f32x4 z = {0.f, 0.f, 0.f, 0.f};
  f32x4 acc[4];
#pragma unroll
  for (int ct = 0; ct < 4; ++ct) acc[ct] = z;
#pragma unroll
  for (int kc = 0; kc < 4; ++kc) {
    bf16x8 afr = *(const bf16x8*)(vT + (wid * 16 + l16) * 136 + kc * 32 + quad * 8);
#pragma unroll
    for (int ct = 0; ct < 4; ++ct) {
      bf16x8 bfr = *(const bf16x8*)(kT + (ct * 16 + l16) * 136 + kc * 32 + quad * 8);
      acc[ct] = __builtin_amdgcn_mfma_f32_16x16x32_bf16(afr, bfr, acc[ct], 0, 0, 0);
    }
  }

  float* outp = mlocT + ((size_t)bh * 16 + c) * 4096;
#pragma unroll
  for (int ct = 0; ct < 4; ++ct)
#pragma unroll
    for (int r = 0; r < 4; ++r)
      outp[(wid * 16 + quad * 4 + r) * 64 + ct * 16 + l16] = acc[ct][r];
}

// Exclusive prefix over chunks, parallel over 4096 (e,f) entries per bh.
__global__ __launch_bounds__(256) void kv_prefix(const float* __restrict__ mlocT,
                                                 ushort* __restrict__ statesT) {
  const int slice = blockIdx.x, bh = blockIdx.y;
  const int eidx = slice * 256 + threadIdx.x;
  float run = 0.f;
  for (int c = 0; c < 16; ++c) {
    const size_t idx = ((size_t)bh * 16 + c) * 4096 + eidx;
    statesT[idx] = f2bf(run);
    run += mlocT[idx];
  }
}

// Per-(bh,chunk): P = tril(Q K^T) ; Y = P V + Q S_prefix (state from statesT).
// R10: causal load-balance -- wave wid owns row-tiles {wid, 7-wid} so QK^T
// work is 9 tile-units/wave (was 4wid+3: wave3 did 5x wave0, barriers waited
// on it) and PV is 20 MFMAs/wave uniform. V transpose packed b32 (16 vs 32).
__global__ __launch_bounds__(256) void attn_chunk(const ushort* __restrict__ qkv,
                                                  const ushort* __restrict__ statesT,
                                                  ushort* __restrict__ yb) {
  const int c = blockIdx.x, bh = blockIdx.y;
  const int b = bh >> 4, hd = bh & 15;
  const int l0 = c * 128;
  const int t = threadIdx.x;
  const int wid = t >> 6, lane = t & 63;
  const int quad = lane >> 4, l16 = lane & 15;

  __shared__ ushort P[16384];  // [row][16B chunks] XOR-swizzled by row&7
  __shared__ ushort U[16384];
  ushort* Qs = U;              // [row:128][64] chunk^(row&7)
  ushort* Ks = U + 8192;
  ushort* vT = U;              // phase2: [e:64][s:128] stride 136
  ushort* sT = U + 8704;       // phase2: [e:64][f:64]  stride 72

  {  // zero P
    uint4 zz; zz.x = zz.y = zz.z = zz.w = 0u;
    uint4* p4 = (uint4*)P;
#pragma unroll
    for (int i = 0; i < 8; ++i) p4[i * 256 + t] = zz;
  }
  {  // stage Q,K swizzled
    const int kcs = ((lane & 7) ^ (lane >> 3)) * 8;
    const ushort* qg = qkv + (size_t)(b * 2048 + l0 + (t >> 3)) * 3072 + hd * 64 + kcs;
    ushort* ql = Qs + wid * 512;
    ushort* kl = Ks + wid * 512;
#pragma unroll
    for (int h2 = 0; h2 < 4; ++h2) {
      glds16(qg + (size_t)h2 * 32 * 3072, ql + h2 * 2048);
      glds16(qg + (size_t)h2 * 32 * 3072 + 1024, kl + h2 * 2048);
    }
  }
  __syncthreads();

  bf16x8 qf[2][2];
#pragma unroll
  for (int i = 0; i < 2; ++i) {
    const int rt = i ? (7 - wid) : wid;
#pragma unroll
    for (int kc = 0; kc < 2; ++kc)
      qf[i][kc] = *(const bf16x8*)(Qs + (rt * 16 + l16) * 64 +
                                   (((kc * 4 + quad) ^ (l16 & 7)) * 8));
  }

  const f32x4 z4 = {0.f, 0.f, 0.f, 0.f};
  f32x4 pacc[2][8];
#pragma unroll
  for (int i = 0; i < 2; ++i)
#pragma unroll
    for (int j = 0; j < 8; ++j) pacc[i][j] = z4;

#pragma unroll
  for (int i = 0; i < 2; ++i) {
    const int rt = i ? (7 - wid) : wid;
#pragma unroll
    for (int tj = 0; tj < 8; ++tj) {
      if (tj <= rt) {
#pragma unroll
        for (int kc = 0; kc < 2; ++kc) {
          bf16x8 kfr = *(const bf16x8*)(Ks + (tj * 16 + l16) * 64 +
                                        (((kc * 4 + quad) ^ (l16 & 7)) * 8));
          pacc[i][tj] = __builtin_amdgcn_mfma_f32_16x16x32_bf16(qf[i][kc], kfr, pacc[i][tj], 0, 0, 0);
        }
      }
    }
  }
  __syncthreads();

#pragma unroll
  for (int i = 0; i < 2; ++i) {
    const int rt = i ? (7 - wid) : wid;
#pragma unroll
    for (int tj = 0; tj < 8; ++tj) {
      if (tj <= rt) {
#pragma unroll
        for (int r = 0; r < 4; ++r) {
          const int row = rt * 16 + quad * 4 + r;
          const int scol = tj * 16 + l16;
          const float v = (scol <= row) ? pacc[i][tj][r] : 0.f;
          P[row * 128 + (((scol >> 3) ^ (row & 7)) * 8) + (scol & 7)] = f2bf(v);
        }
      }
    }
  }
  {  // stage V transposed: vT[e][s] stride 136, s-pair-packed b32 writes
    const int p = t >> 2;              // s-pair: s = 2p, 2p+1
    const int eq = (t & 3) * 16;       // e-quarter
    const ushort* vg0 = qkv + (size_t)(b * 2048 + l0 + 2 * p) * 3072 + 2048 + hd * 64 + eq;
    const ushort* vg1 = vg0 + 3072;
    ushort ta[16], tb[16];
    *(uint4*)(ta + 0) = *(const uint4*)(vg0 + 0);
    *(uint4*)(ta + 8) = *(const uint4*)(vg0 + 8);
    *(uint4*)(tb + 0) = *(const uint4*)(vg1 + 0);
    *(uint4*)(tb + 8) = *(const uint4*)(vg1 + 8);
#pragma unroll
    for (int j = 0; j < 16; ++j) {
      unsigned pk = (unsigned)ta[j] | ((unsigned)tb[j] << 16);
      *(unsigned*)(vT + (eq + j) * 136 + 2 * p) = pk;
    }
  }
  {  // stage state: 2 coalesced uint4 per thread -> sT stride 72
    const ushort* sg = statesT + ((size_t)bh * 16 + c) * 4096;
#pragma unroll
    for (int h = 0; h < 2; ++h) {
      const int cc = h * 256 + t;
      uint4 d = *(const uint4*)(sg + cc * 8);
      *(uint4*)(sT + (cc >> 3) * 72 + (cc & 7) * 8) = d;
    }
  }
  __syncthreads();

  f32x4 yacc[2][4];
#pragma unroll
  for (int i = 0; i < 2; ++i)
#pragma unroll
    for (int j = 0; j < 4; ++j) yacc[i][j] = z4;

#pragma unroll
  for (int i = 0; i < 2; ++i) {
    const int rt = i ? (7 - wid) : wid;
    const int kcmax = rt >> 1;
#pragma unroll
    for (int kc = 0; kc < 4; ++kc) {
      if (kc <= kcmax) {
        const int prow = rt * 16 + l16;
        bf16x8 pf;
        *(uint4*)&pf = *(const uint4*)(P + prow * 128 + (((kc * 4 + quad) ^ (prow & 7)) * 8));
#pragma unroll
        for (int ct = 0; ct < 4; ++ct) {
          bf16x8 vf = *(const bf16x8*)(vT + (ct * 16 + l16) * 136 + kc * 32 + quad * 8);
          yacc[i][ct] = __builtin_amdgcn_mfma_f32_16x16x32_bf16(pf, vf, yacc[i][ct], 0, 0, 0);
        }
      }
    }
#pragma unroll
    for (int kc = 0; kc < 2; ++kc) {
#pragma unroll
      for (int ct = 0; ct < 4; ++ct) {
        bf16x8 sf = *(const bf16x8*)(sT + (ct * 16 + l16) * 72 + kc * 32 + quad * 8);
        yacc[i][ct] = __builtin_amdgcn_mfma_f32_16x16x32_bf16(qf[i][kc], sf, yacc[i][ct], 0, 0, 0);
      }
    }
  }

#pragma unroll
  for (int i = 0; i < 2; ++i) {
    const int rt = i ? (7 - wid) : wid;
#pragma unroll
    for (int ct = 0; ct < 4; ++ct) {
#pragma unroll
      for (int r = 0; r < 4; ++r) {
        const int row = rt * 16 + quad * 4 + r;
        const int e = ct * 16 + l16;
        yb[(size_t)(b * 2048 + l0 + row) * 1024 + hd * 64 + e] = f2bf(yacc[i][ct][r]);
      }
    }
  }
}

extern "C" void kernel_launch(void* const* d_in, const int* in_sizes, int n_in,
                              void* d_out, int out_size, void* d_ws, size_t ws_size,
                              hipStream_t stream) {
  const float* x  = (const float*)d_in[0];
  const float* Ww = (const float*)d_in[1];
  const float* Wb = (const float*)d_in[2];
  const float* Ow = (const float*)d_in[3];
  const float* Ob = (const float*)d_in[4];
  float* out = (float*)d_out;

  char* ws = (char*)d_ws;
  ushort* xb      = (ushort*)(ws);
  ushort* wqkvb   = (ushort*)(ws + (size_t)8  * 1024 * 1024);
  ushort* outwb   = (ushort*)(ws + (size_t)14 * 1024 * 1024);
  ushort* qkvb    = (ushort*)(ws + (size_t)16 * 1024 * 1024);
  float*  mlocT   = (float*) (ws + (size_t)40 * 1024 * 1024);
  ushort* statesT = (ushort*)(ws + (size_t)48 * 1024 * 1024);
  ushort* yb      = (ushort*)(ws + (size_t)52 * 1024 * 1024);

  cvt_all<<<8192, 256, 0, stream>>>(x, Ww, Ow, xb, wqkvb, outwb);
  // 256^2 tiles: grid = (3072/256)*(4096/256) = 192 blocks (1D, XCD-swizzled).
  gemm_bt8<true, true><<<dim3(192), 512, 0, stream>>>(xb, wqkvb, Wb, (void*)qkvb, 4096, 3072, 1024);
  kv_local<<<dim3(16, 32), 256, 0, stream>>>(qkvb, mlocT);
  kv_prefix<<<dim3(16, 32), 256, 0, stream>>>(mlocT, statesT);
  attn_chunk<<<dim3(16, 32), 256, 0, stream>>>(qkvb, statesT, yb);
  gemm_out64<<<dim3(8, 64), 256, 0, stream>>>(yb, outwb, Ob, out, 4096, 1024, 1024);
}